// Round 2
// baseline (2206.444 us; speedup 1.0000x reference)
//
#include <hip/hip_runtime.h>
#include <hip/hip_bf16.h>

#define DIVUP(a, b) (((a) + (b) - 1) / (b))

// ---------- helpers ----------
__device__ __forceinline__ float bf2f(unsigned short u) {
    union { unsigned int i; float f; } v;
    v.i = ((unsigned int)u) << 16;
    return v.f;
}

// dtype-adaptive scalar load: isbf=1 -> bf16, isbf=0 -> f32
__device__ __forceinline__ float gload(const void* p, int i, int isbf) {
    return isbf ? bf2f(((const unsigned short*)p)[i]) : ((const float*)p)[i];
}

// ---------- dtype detection ----------
// Features ~ N(0,1). If buffer is bf16, even-indexed bf16 elements are N(0,1)
// samples (~100% of |v| in [1e-4,10]). If buffer is f32, even bf16 indices are
// low mantissa halves -> random exponent, ~7% in range. flag=1 means bf16.
__global__ void __launch_bounds__(256) detect_dtype(const void* __restrict__ feat,
                                                    int* __restrict__ flag) {
    __shared__ int cnt;
    if (threadIdx.x == 0) cnt = 0;
    __syncthreads();
    const unsigned short* u = (const unsigned short*)feat;
    int c = 0;
#pragma unroll
    for (int rep = 0; rep < 4; ++rep) {
        const int idx = threadIdx.x * 2 + rep * 512;   // even indices 0..2046
        const float v = fabsf(bf2f(u[idx]));
        c += (v > 1e-4f && v < 10.0f) ? 1 : 0;
    }
    atomicAdd(&cnt, c);
    __syncthreads();
    if (threadIdx.x == 0) *flag = (cnt > 512) ? 1 : 0;
}

// ---------- degree / norm ----------
__global__ void __launch_bounds__(256) count_deg(const int* __restrict__ col,
                                                 float* __restrict__ deg, int nE) {
    int e = blockIdx.x * 256 + threadIdx.x;
    if (e < nE) atomicAdd(&deg[col[e]], 1.0f);
}

__global__ void __launch_bounds__(256) make_dinv(float* __restrict__ deg, int n) {
    int i = blockIdx.x * 256 + threadIdx.x;
    if (i < n) deg[i] = rsqrtf(deg[i] + 1.0f);   // +1 self-loop
}

// ---------- GEMM: y = (x @ W) * dinv[node] ----------
// XDYN: x dtype decided by flag (layer 1); otherwise x is f32 (internal buffer).
// W is always dtype-dynamic (raw input).
template<int F_IN, int F_OUT, bool XDYN>
__global__ void __launch_bounds__(256) gemm_scale(const void* __restrict__ x,
                                                  const void* __restrict__ W,
                                                  const float* __restrict__ dinv,
                                                  float* __restrict__ y, int n,
                                                  const int* __restrict__ flag) {
    const int isbf = *flag;
    __shared__ float Ws[F_IN * F_OUT];
    for (int i = threadIdx.x; i < F_IN * F_OUT; i += 256)
        Ws[i] = gload(W, i, isbf);
    __syncthreads();

    constexpr int NPB = 256 / F_OUT;
    const int f    = threadIdx.x % F_OUT;
    const int node = blockIdx.x * NPB + threadIdx.x / F_OUT;
    if (node >= n) return;

    float acc = 0.f;
    if (XDYN && isbf) {
        const unsigned short* xr = (const unsigned short*)x + (size_t)node * F_IN;
#pragma unroll
        for (int k4 = 0; k4 < F_IN / 4; ++k4) {
            const ushort4 u = *(const ushort4*)(xr + k4 * 4);
            acc = fmaf(bf2f(u.x), Ws[(k4 * 4 + 0) * F_OUT + f], acc);
            acc = fmaf(bf2f(u.y), Ws[(k4 * 4 + 1) * F_OUT + f], acc);
            acc = fmaf(bf2f(u.z), Ws[(k4 * 4 + 2) * F_OUT + f], acc);
            acc = fmaf(bf2f(u.w), Ws[(k4 * 4 + 3) * F_OUT + f], acc);
        }
    } else {
        const float* xr = (const float*)x + (size_t)node * F_IN;
#pragma unroll
        for (int k4 = 0; k4 < F_IN / 4; ++k4) {
            const float4 xv = *(const float4*)(xr + k4 * 4);
            acc = fmaf(xv.x, Ws[(k4 * 4 + 0) * F_OUT + f], acc);
            acc = fmaf(xv.y, Ws[(k4 * 4 + 1) * F_OUT + f], acc);
            acc = fmaf(xv.z, Ws[(k4 * 4 + 2) * F_OUT + f], acc);
            acc = fmaf(xv.w, Ws[(k4 * 4 + 3) * F_OUT + f], acc);
        }
    }
    y[(size_t)node * F_OUT + f] = acc * dinv[node];
}

// ---------- edge scatter: s[col] += y[row] (atomics) ----------
template<int F>
__global__ void __launch_bounds__(256) scatter_add(const int* __restrict__ row,
                                                   const int* __restrict__ col,
                                                   const float* __restrict__ y,
                                                   float* __restrict__ s, int nE) {
    const int t = blockIdx.x * 256 + threadIdx.x;
    const int e = t / F;
    const int f = t % F;
    if (e < nE) {
        const int r = row[e];
        const int c = col[e];
        atomicAdd(&s[(size_t)c * F + f], y[(size_t)r * F + f]);
    }
}

// ---------- epilogue (in-place on s): s = relu(dinv*(s + y) + b) ----------
template<int F>
__global__ void __launch_bounds__(256) epilogue_relu(float* __restrict__ s,
                                                     const float* __restrict__ y,
                                                     const float* __restrict__ dinv,
                                                     const void* __restrict__ b,
                                                     int n, const int* __restrict__ flag) {
    const int isbf = *flag;
    const int t = blockIdx.x * 256 + threadIdx.x;
    const int node = t / F;
    const int f    = t % F;
    if (node < n) {
        const float v = dinv[node] * (s[t] + y[t]) + gload(b, f, isbf);
        s[t] = fmaxf(v, 0.f);
    }
}

// ---------- dense head: out = relu(concat(f1,f2,f3) @ Wfc + bfc) ----------
__global__ void __launch_bounds__(256) head_kernel(const float* __restrict__ f1,
                                                   const float* __restrict__ f2,
                                                   const float* __restrict__ f3,
                                                   const void* __restrict__ Wfc,
                                                   const void* __restrict__ bfc,
                                                   void* __restrict__ out, int n,
                                                   const int* __restrict__ flag) {
    const int isbf = *flag;
    __shared__ float Ws[112 * 16];
    for (int i = threadIdx.x; i < 112 * 16; i += 256)
        Ws[i] = gload(Wfc, i, isbf);
    __syncthreads();

    const int f    = threadIdx.x & 15;
    const int node = blockIdx.x * 16 + (threadIdx.x >> 4);
    if (node >= n) return;

    float acc = gload(bfc, f, isbf);
    const float* x1 = f1 + (size_t)node * 64;
#pragma unroll
    for (int k = 0; k < 64; ++k) acc = fmaf(x1[k], Ws[k * 16 + f], acc);
    const float* x2 = f2 + (size_t)node * 32;
#pragma unroll
    for (int k = 0; k < 32; ++k) acc = fmaf(x2[k], Ws[(64 + k) * 16 + f], acc);
    const float* x3 = f3 + (size_t)node * 16;
#pragma unroll
    for (int k = 0; k < 16; ++k) acc = fmaf(x3[k], Ws[(96 + k) * 16 + f], acc);

    const float r = fmaxf(acc, 0.f);
    const size_t o = (size_t)node * 16 + f;
    if (isbf) ((__hip_bfloat16*)out)[o] = __float2bfloat16(r);
    else      ((float*)out)[o] = r;
}

// ---------- launch ----------
extern "C" void kernel_launch(void* const* d_in, const int* in_sizes, int n_in,
                              void* d_out, int out_size, void* d_ws, size_t ws_size,
                              hipStream_t stream) {
    const int*  edges = (const int*)d_in[0];
    const void* feat  = d_in[1];
    const void* W1    = d_in[2];
    const void* b1    = d_in[3];
    const void* W2    = d_in[4];
    const void* b2    = d_in[5];
    const void* W3    = d_in[6];
    const void* b3    = d_in[7];
    const void* Wfc   = d_in[8];
    const void* bfc   = d_in[9];

    const int E = in_sizes[0] / 2;
    const int N = in_sizes[1] / 128;
    const int* row = edges;
    const int* col = edges + E;

    // workspace layout (f32 elements):
    // [0..3]: flag | dinv[N] | y[64N] | s1[64N] | s2[32N] | s3[16N]
    // epilogue is in-place: f1=s1, f2=s2, f3=s3. Total = 4 + 177N floats (~71 MB).
    int*   flag = (int*)d_ws;
    float* base = (float*)d_ws;
    float* dinv = base + 4;
    float* y    = dinv + N;
    float* s1   = y  + (size_t)N * 64;
    float* s2   = s1 + (size_t)N * 64;
    float* s3   = s2 + (size_t)N * 32;

    detect_dtype<<<1, 256, 0, stream>>>(feat, flag);

    // normalization coefficients
    hipMemsetAsync(dinv, 0, (size_t)N * sizeof(float), stream);
    count_deg<<<DIVUP(E, 256), 256, 0, stream>>>(col, dinv, E);
    make_dinv<<<DIVUP(N, 256), 256, 0, stream>>>(dinv, N);

    // layer 1: 128 -> 64
    gemm_scale<128, 64, true><<<DIVUP(N, 4), 256, 0, stream>>>(feat, W1, dinv, y, N, flag);
    hipMemsetAsync(s1, 0, (size_t)N * 64 * sizeof(float), stream);
    scatter_add<64><<<DIVUP(E * 64, 256), 256, 0, stream>>>(row, col, y, s1, E);
    epilogue_relu<64><<<DIVUP(N * 64, 256), 256, 0, stream>>>(s1, y, dinv, b1, N, flag);

    // layer 2: 64 -> 32
    gemm_scale<64, 32, false><<<DIVUP(N, 8), 256, 0, stream>>>(s1, W2, dinv, y, N, flag);
    hipMemsetAsync(s2, 0, (size_t)N * 32 * sizeof(float), stream);
    scatter_add<32><<<DIVUP(E * 32, 256), 256, 0, stream>>>(row, col, y, s2, E);
    epilogue_relu<32><<<DIVUP(N * 32, 256), 256, 0, stream>>>(s2, y, dinv, b2, N, flag);

    // layer 3: 32 -> 16
    gemm_scale<32, 16, false><<<DIVUP(N, 16), 256, 0, stream>>>(s2, W3, dinv, y, N, flag);
    hipMemsetAsync(s3, 0, (size_t)N * 16 * sizeof(float), stream);
    scatter_add<16><<<DIVUP(E * 16, 256), 256, 0, stream>>>(row, col, y, s3, E);
    epilogue_relu<16><<<DIVUP(N * 16, 256), 256, 0, stream>>>(s3, y, dinv, b3, N, flag);

    // dense head
    head_kernel<<<DIVUP(N, 16), 256, 0, stream>>>(s1, s2, s3, Wfc, bfc, d_out, N, flag);
}

// Round 3
// 999.935 us; speedup vs baseline: 2.2066x; 2.2066x over previous
//
#include <hip/hip_runtime.h>
#include <hip/hip_bf16.h>

#define DIVUP(a, b) (((a) + (b) - 1) / (b))

// ---------- helpers ----------
__device__ __forceinline__ float bf2f(unsigned short u) {
    union { unsigned int i; float f; } v;
    v.i = ((unsigned int)u) << 16;
    return v.f;
}

// dtype-adaptive scalar load: isbf=1 -> bf16, isbf=0 -> f32
__device__ __forceinline__ float gload(const void* p, int i, int isbf) {
    return isbf ? bf2f(((const unsigned short*)p)[i]) : ((const float*)p)[i];
}

// ---------- dtype detection ----------
// Features ~ N(0,1). If buffer is bf16, even-indexed bf16 elements are N(0,1)
// samples (~100% of |v| in [1e-4,10]). If buffer is f32, even bf16 indices are
// low mantissa halves -> random exponent, ~7% in range. flag=1 means bf16.
__global__ void __launch_bounds__(256) detect_dtype(const void* __restrict__ feat,
                                                    int* __restrict__ flag) {
    __shared__ int cnt;
    if (threadIdx.x == 0) cnt = 0;
    __syncthreads();
    const unsigned short* u = (const unsigned short*)feat;
    int c = 0;
#pragma unroll
    for (int rep = 0; rep < 4; ++rep) {
        const int idx = threadIdx.x * 2 + rep * 512;   // even indices
        const float v = fabsf(bf2f(u[idx]));
        c += (v > 1e-4f && v < 10.0f) ? 1 : 0;
    }
    atomicAdd(&cnt, c);
    __syncthreads();
    if (threadIdx.x == 0) *flag = (cnt > 512) ? 1 : 0;
}

// ---------- degree count (int) ----------
__global__ void __launch_bounds__(256) count_deg(const int* __restrict__ col,
                                                 int* __restrict__ cnt, int nE) {
    int e = blockIdx.x * 256 + threadIdx.x;
    if (e < nE) atomicAdd(&cnt[col[e]], 1);
}

__global__ void __launch_bounds__(256) make_dinv(const int* __restrict__ cnt,
                                                 float* __restrict__ dinv, int n) {
    int i = blockIdx.x * 256 + threadIdx.x;
    if (i < n) dinv[i] = rsqrtf((float)cnt[i] + 1.0f);   // +1 self-loop
}

// ---------- exclusive scan of cnt[N] -> rowptr[N] (3-phase) ----------
// phase 1: per-1024-chunk sums
__global__ void __launch_bounds__(256) scan_block_sums(const int* __restrict__ cnt,
                                                       int* __restrict__ bsum, int n) {
    __shared__ int red[256];
    const int base = blockIdx.x * 1024;
    int s = 0;
    for (int i = threadIdx.x; i < 1024; i += 256) {
        const int idx = base + i;
        s += (idx < n) ? cnt[idx] : 0;
    }
    red[threadIdx.x] = s;
    __syncthreads();
    for (int off = 128; off > 0; off >>= 1) {
        if (threadIdx.x < off) red[threadIdx.x] += red[threadIdx.x + off];
        __syncthreads();
    }
    if (threadIdx.x == 0) bsum[blockIdx.x] = red[0];
}

// phase 2: exclusive scan of bsum (single block; nb <= 256)
__global__ void __launch_bounds__(256) scan_bsum(int* __restrict__ bsum, int nb) {
    __shared__ int tmp[256];
    const int x = threadIdx.x;
    const int v = (x < nb) ? bsum[x] : 0;
    tmp[x] = v;
    __syncthreads();
    int val = v;
    for (int off = 1; off < 256; off <<= 1) {
        const int t = (x >= off) ? tmp[x - off] : 0;
        __syncthreads();
        val += t;
        tmp[x] = val;
        __syncthreads();
    }
    if (x < nb) bsum[x] = val - v;   // exclusive
}

// phase 3: final exclusive scan per chunk, + chunk offset
__global__ void __launch_bounds__(256) scan_final(const int* __restrict__ cnt,
                                                  const int* __restrict__ bsum,
                                                  int* __restrict__ rowptr, int n) {
    __shared__ int tsum[256];
    const int base = blockIdx.x * 1024;
    const int x = threadIdx.x;
    int v[4];
    int s = 0;
#pragma unroll
    for (int k = 0; k < 4; ++k) {
        const int idx = base + x * 4 + k;
        v[k] = (idx < n) ? cnt[idx] : 0;
        s += v[k];
    }
    tsum[x] = s;
    __syncthreads();
    int val = s;
    for (int off = 1; off < 256; off <<= 1) {
        const int t = (x >= off) ? tsum[x - off] : 0;
        __syncthreads();
        val += t;
        tsum[x] = val;
        __syncthreads();
    }
    int prefix = bsum[blockIdx.x] + (val - s);   // exclusive prefix for this thread
#pragma unroll
    for (int k = 0; k < 4; ++k) {
        const int idx = base + x * 4 + k;
        if (idx < n) rowptr[idx] = prefix;
        prefix += v[k];
    }
}

// ---------- CSR fill ----------
__global__ void __launch_bounds__(256) csr_fill(const int* __restrict__ row,
                                                const int* __restrict__ col,
                                                const int* __restrict__ rowptr,
                                                int* __restrict__ cursor,
                                                int* __restrict__ csr, int nE) {
    const int e = blockIdx.x * 256 + threadIdx.x;
    if (e < nE) {
        const int c = col[e];
        const int p = atomicAdd(&cursor[c], 1);
        csr[rowptr[c] + p] = row[e];
    }
}

// ---------- GEMM: y = (x @ W) * dinv[node] ----------
template<int F_IN, int F_OUT, bool XDYN>
__global__ void __launch_bounds__(256) gemm_scale(const void* __restrict__ x,
                                                  const void* __restrict__ W,
                                                  const float* __restrict__ dinv,
                                                  float* __restrict__ y, int n,
                                                  const int* __restrict__ flag) {
    const int isbf = *flag;
    __shared__ float Ws[F_IN * F_OUT];
    for (int i = threadIdx.x; i < F_IN * F_OUT; i += 256)
        Ws[i] = gload(W, i, isbf);
    __syncthreads();

    constexpr int NPB = 256 / F_OUT;
    const int f    = threadIdx.x % F_OUT;
    const int node = blockIdx.x * NPB + threadIdx.x / F_OUT;
    if (node >= n) return;

    float acc = 0.f;
    if (XDYN && isbf) {
        const unsigned short* xr = (const unsigned short*)x + (size_t)node * F_IN;
#pragma unroll
        for (int k4 = 0; k4 < F_IN / 4; ++k4) {
            const ushort4 u = *(const ushort4*)(xr + k4 * 4);
            acc = fmaf(bf2f(u.x), Ws[(k4 * 4 + 0) * F_OUT + f], acc);
            acc = fmaf(bf2f(u.y), Ws[(k4 * 4 + 1) * F_OUT + f], acc);
            acc = fmaf(bf2f(u.z), Ws[(k4 * 4 + 2) * F_OUT + f], acc);
            acc = fmaf(bf2f(u.w), Ws[(k4 * 4 + 3) * F_OUT + f], acc);
        }
    } else {
        const float* xr = (const float*)x + (size_t)node * F_IN;
#pragma unroll
        for (int k4 = 0; k4 < F_IN / 4; ++k4) {
            const float4 xv = *(const float4*)(xr + k4 * 4);
            acc = fmaf(xv.x, Ws[(k4 * 4 + 0) * F_OUT + f], acc);
            acc = fmaf(xv.y, Ws[(k4 * 4 + 1) * F_OUT + f], acc);
            acc = fmaf(xv.z, Ws[(k4 * 4 + 2) * F_OUT + f], acc);
            acc = fmaf(xv.w, Ws[(k4 * 4 + 3) * F_OUT + f], acc);
        }
    }
    y[(size_t)node * F_OUT + f] = acc * dinv[node];
}

// ---------- aggregate + fused epilogue ----------
// out[c,f] = relu(dinv[c] * (sum_{r in csr[c]} y[r,f] + y[c,f]) + b[f])
// 64/F node-groups per wave; each group's F lanes gather full y rows.
template<int F>
__global__ void __launch_bounds__(256) aggregate(const float* __restrict__ y,
                                                 const int* __restrict__ csr,
                                                 const int* __restrict__ rowptr,
                                                 const int* __restrict__ cnt,
                                                 const float* __restrict__ dinv,
                                                 const void* __restrict__ b,
                                                 float* __restrict__ out, int n,
                                                 const int* __restrict__ flag) {
    const int isbf = *flag;
    constexpr int GP = 64 / F;                       // node groups per wave
    const int lane = threadIdx.x & 63;
    const int sub  = lane / F;
    const int f    = lane % F;
    const int wave = (blockIdx.x * 256 + threadIdx.x) >> 6;
    const int node = wave * GP + sub;
    if (node >= n) return;

    const int beg = rowptr[node];
    const int deg = cnt[node];
    float acc = 0.f;
    int j = 0;
    for (; j + 4 <= deg; j += 4) {
        const int s0 = csr[beg + j + 0];
        const int s1 = csr[beg + j + 1];
        const int s2 = csr[beg + j + 2];
        const int s3 = csr[beg + j + 3];
        const float v0 = y[(size_t)s0 * F + f];
        const float v1 = y[(size_t)s1 * F + f];
        const float v2 = y[(size_t)s2 * F + f];
        const float v3 = y[(size_t)s3 * F + f];
        acc += (v0 + v1) + (v2 + v3);
    }
    for (; j < deg; ++j) acc += y[(size_t)csr[beg + j] * F + f];

    const float v = dinv[node] * (acc + y[(size_t)node * F + f]) + gload(b, f, isbf);
    out[(size_t)node * F + f] = fmaxf(v, 0.f);
}

// ---------- dense head: out = relu(concat(f1,f2,f3) @ Wfc + bfc) ----------
__global__ void __launch_bounds__(256) head_kernel(const float* __restrict__ f1,
                                                   const float* __restrict__ f2,
                                                   const float* __restrict__ f3,
                                                   const void* __restrict__ Wfc,
                                                   const void* __restrict__ bfc,
                                                   void* __restrict__ out, int n,
                                                   const int* __restrict__ flag) {
    const int isbf = *flag;
    __shared__ float Ws[112 * 16];
    for (int i = threadIdx.x; i < 112 * 16; i += 256)
        Ws[i] = gload(Wfc, i, isbf);
    __syncthreads();

    const int f    = threadIdx.x & 15;
    const int node = blockIdx.x * 16 + (threadIdx.x >> 4);
    if (node >= n) return;

    float acc = gload(bfc, f, isbf);
    const float* x1 = f1 + (size_t)node * 64;
#pragma unroll
    for (int k = 0; k < 64; ++k) acc = fmaf(x1[k], Ws[k * 16 + f], acc);
    const float* x2 = f2 + (size_t)node * 32;
#pragma unroll
    for (int k = 0; k < 32; ++k) acc = fmaf(x2[k], Ws[(64 + k) * 16 + f], acc);
    const float* x3 = f3 + (size_t)node * 16;
#pragma unroll
    for (int k = 0; k < 16; ++k) acc = fmaf(x3[k], Ws[(96 + k) * 16 + f], acc);

    const float r = fmaxf(acc, 0.f);
    const size_t o = (size_t)node * 16 + f;
    if (isbf) ((__hip_bfloat16*)out)[o] = __float2bfloat16(r);
    else      ((float*)out)[o] = r;
}

// ---------- launch ----------
extern "C" void kernel_launch(void* const* d_in, const int* in_sizes, int n_in,
                              void* d_out, int out_size, void* d_ws, size_t ws_size,
                              hipStream_t stream) {
    const int*  edges = (const int*)d_in[0];
    const void* feat  = d_in[1];
    const void* W1    = d_in[2];
    const void* b1    = d_in[3];
    const void* W2    = d_in[4];
    const void* b2    = d_in[5];
    const void* W3    = d_in[6];
    const void* b3    = d_in[7];
    const void* Wfc   = d_in[8];
    const void* bfc   = d_in[9];

    const int E = in_sizes[0] / 2;
    const int N = in_sizes[1] / 128;
    const int* row = edges;
    const int* col = edges + E;

    // workspace layout (~85 MB):
    // flag | dinv[N] | cnt[N] | cursor[N] | rowptr[N] | csr[E] | y[64N] | f1[64N] | f2[32N] | f3[16N]
    char* p = (char*)d_ws;
    int*   flag   = (int*)p;              p += 16;
    float* dinv   = (float*)p;            p += (size_t)N * 4;
    int*   cnt    = (int*)p;              p += (size_t)N * 4;
    int*   cursor = (int*)p;              p += (size_t)N * 4;
    int*   rowptr = (int*)p;              p += (size_t)N * 4;
    int*   csr    = (int*)p;              p += (size_t)E * 4;
    float* y      = (float*)p;            p += (size_t)N * 64 * 4;
    float* f1     = (float*)p;            p += (size_t)N * 64 * 4;
    float* f2     = (float*)p;            p += (size_t)N * 32 * 4;
    float* f3     = (float*)p;            p += (size_t)N * 16 * 4;

    detect_dtype<<<1, 256, 0, stream>>>(feat, flag);

    // degrees + norm
    hipMemsetAsync(cnt, 0, (size_t)N * sizeof(int), stream);
    hipMemsetAsync(cursor, 0, (size_t)N * sizeof(int), stream);
    count_deg<<<DIVUP(E, 256), 256, 0, stream>>>(col, cnt, E);
    make_dinv<<<DIVUP(N, 256), 256, 0, stream>>>(cnt, dinv, N);

    // CSR build: scan + fill
    const int nb = DIVUP(N, 1024);
    int* bsum = cursor;  // NO — cursor must stay zero. Use a separate slot:
    bsum = (int*)p;      // 4*nb bytes past f3 (nb <= 256 -> 1 KB)
    scan_block_sums<<<nb, 256, 0, stream>>>(cnt, bsum, N);
    scan_bsum<<<1, 256, 0, stream>>>(bsum, nb);
    scan_final<<<nb, 256, 0, stream>>>(cnt, bsum, rowptr, N);
    csr_fill<<<DIVUP(E, 256), 256, 0, stream>>>(row, col, rowptr, cursor, csr, E);

    // layer 1: 128 -> 64
    gemm_scale<128, 64, true><<<DIVUP(N, 4), 256, 0, stream>>>(feat, W1, dinv, y, N, flag);
    aggregate<64><<<DIVUP(N, 4), 256, 0, stream>>>(y, csr, rowptr, cnt, dinv, b1, f1, N, flag);

    // layer 2: 64 -> 32
    gemm_scale<64, 32, false><<<DIVUP(N, 8), 256, 0, stream>>>(f1, W2, dinv, y, N, flag);
    aggregate<32><<<DIVUP(N, 8), 256, 0, stream>>>(y, csr, rowptr, cnt, dinv, b2, f2, N, flag);

    // layer 3: 32 -> 16
    gemm_scale<32, 16, false><<<DIVUP(N, 16), 256, 0, stream>>>(f2, W3, dinv, y, N, flag);
    aggregate<16><<<DIVUP(N, 16), 256, 0, stream>>>(y, csr, rowptr, cnt, dinv, b3, f3, N, flag);

    // dense head
    head_kernel<<<DIVUP(N, 16), 256, 0, stream>>>(f1, f2, f3, Wfc, bfc, d_out, N, flag);
}

// Round 4
// 799.594 us; speedup vs baseline: 2.7595x; 1.2506x over previous
//
#include <hip/hip_runtime.h>
#include <hip/hip_bf16.h>

#define DIVUP(a, b) (((a) + (b) - 1) / (b))

// ---------- helpers ----------
__device__ __forceinline__ float bf2f(unsigned short u) {
    union { unsigned int i; float f; } v;
    v.i = ((unsigned int)u) << 16;
    return v.f;
}

// dtype-adaptive scalar load: isbf=1 -> bf16, isbf=0 -> f32
__device__ __forceinline__ float gload(const void* p, int i, int isbf) {
    return isbf ? bf2f(((const unsigned short*)p)[i]) : ((const float*)p)[i];
}

// ---------- dtype detection ----------
// Features ~ N(0,1). If buffer is bf16, even-indexed bf16 elements are N(0,1)
// samples (~100% of |v| in [1e-4,10]). If buffer is f32, even bf16 indices are
// low mantissa halves -> random exponent, ~7% in range. flag=1 means bf16.
// (Round-0 evidence: reading inputs as bf16 gave inf => inputs are f32; this
// detector picks the f32 path but keeps the kernel robust either way.)
__global__ void __launch_bounds__(256) detect_dtype(const void* __restrict__ feat,
                                                    int* __restrict__ flag) {
    __shared__ int cnt;
    if (threadIdx.x == 0) cnt = 0;
    __syncthreads();
    const unsigned short* u = (const unsigned short*)feat;
    int c = 0;
#pragma unroll
    for (int rep = 0; rep < 4; ++rep) {
        const int idx = threadIdx.x * 2 + rep * 512;   // even indices
        const float v = fabsf(bf2f(u[idx]));
        c += (v > 1e-4f && v < 10.0f) ? 1 : 0;
    }
    atomicAdd(&cnt, c);
    __syncthreads();
    if (threadIdx.x == 0) *flag = (cnt > 512) ? 1 : 0;
}

// ---------- degree count (int) ----------
__global__ void __launch_bounds__(256) count_deg(const int* __restrict__ col,
                                                 int* __restrict__ cnt, int nE) {
    int e = blockIdx.x * 256 + threadIdx.x;
    if (e < nE) atomicAdd(&cnt[col[e]], 1);
}

__global__ void __launch_bounds__(256) make_dinv(const int* __restrict__ cnt,
                                                 float* __restrict__ dinv, int n) {
    int i = blockIdx.x * 256 + threadIdx.x;
    if (i < n) dinv[i] = rsqrtf((float)cnt[i] + 1.0f);   // +1 self-loop
}

// ---------- exclusive scan of cnt[N] -> rowptr[N] (3-phase) ----------
__global__ void __launch_bounds__(256) scan_block_sums(const int* __restrict__ cnt,
                                                       int* __restrict__ bsum, int n) {
    __shared__ int red[256];
    const int base = blockIdx.x * 1024;
    int s = 0;
    for (int i = threadIdx.x; i < 1024; i += 256) {
        const int idx = base + i;
        s += (idx < n) ? cnt[idx] : 0;
    }
    red[threadIdx.x] = s;
    __syncthreads();
    for (int off = 128; off > 0; off >>= 1) {
        if (threadIdx.x < off) red[threadIdx.x] += red[threadIdx.x + off];
        __syncthreads();
    }
    if (threadIdx.x == 0) bsum[blockIdx.x] = red[0];
}

__global__ void __launch_bounds__(256) scan_bsum(int* __restrict__ bsum, int nb) {
    __shared__ int tmp[256];
    const int x = threadIdx.x;
    const int v = (x < nb) ? bsum[x] : 0;
    tmp[x] = v;
    __syncthreads();
    int val = v;
    for (int off = 1; off < 256; off <<= 1) {
        const int t = (x >= off) ? tmp[x - off] : 0;
        __syncthreads();
        val += t;
        tmp[x] = val;
        __syncthreads();
    }
    if (x < nb) bsum[x] = val - v;   // exclusive
}

__global__ void __launch_bounds__(256) scan_final(const int* __restrict__ cnt,
                                                  const int* __restrict__ bsum,
                                                  int* __restrict__ rowptr, int n) {
    __shared__ int tsum[256];
    const int base = blockIdx.x * 1024;
    const int x = threadIdx.x;
    int v[4];
    int s = 0;
#pragma unroll
    for (int k = 0; k < 4; ++k) {
        const int idx = base + x * 4 + k;
        v[k] = (idx < n) ? cnt[idx] : 0;
        s += v[k];
    }
    tsum[x] = s;
    __syncthreads();
    int val = s;
    for (int off = 1; off < 256; off <<= 1) {
        const int t = (x >= off) ? tsum[x - off] : 0;
        __syncthreads();
        val += t;
        tsum[x] = val;
        __syncthreads();
    }
    int prefix = bsum[blockIdx.x] + (val - s);
#pragma unroll
    for (int k = 0; k < 4; ++k) {
        const int idx = base + x * 4 + k;
        if (idx < n) rowptr[idx] = prefix;
        prefix += v[k];
    }
}

// ---------- CSR fill ----------
__global__ void __launch_bounds__(256) csr_fill(const int* __restrict__ row,
                                                const int* __restrict__ col,
                                                const int* __restrict__ rowptr,
                                                int* __restrict__ cursor,
                                                int* __restrict__ csr, int nE) {
    const int e = blockIdx.x * 256 + threadIdx.x;
    if (e < nE) {
        const int c = col[e];
        const int p = atomicAdd(&cursor[c], 1);
        csr[rowptr[c] + p] = row[e];
    }
}

// ---------- register-tiled GEMM: y = (x @ W) * dinv[node] ----------
// Block: 256 threads. Thread tile = 4 nodes x 4 f. TILE_N = 4096/F_OUT.
// LDS: Ws[k][F_OUT] + xs[k][TILE_N] (transposed x tile).
// Per k-step per thread: 1 ds_read_b128 (x) + 1 ds_read_b128 (W) + 16 FMA.
template<int F_IN, int F_OUT, bool XDYN>
__global__ void __launch_bounds__(256) gemm_tile(const void* __restrict__ x,
                                                 const void* __restrict__ W,
                                                 const float* __restrict__ dinv,
                                                 float* __restrict__ y, int n,
                                                 const int* __restrict__ flag) {
    constexpr int TILE_N = 4096 / F_OUT;        // 64 / 128 / 256
    const int isbf = *flag;
    __shared__ float Ws[F_IN * F_OUT];
    __shared__ float xs[F_IN * TILE_N];

    const int t = threadIdx.x;
    for (int i = t; i < F_IN * F_OUT; i += 256) Ws[i] = gload(W, i, isbf);

    // stage x tile transposed: xs[k][n_local]; lanes write consecutive n -> conflict-free
    const int nb = blockIdx.x * TILE_N;
    for (int idx = t; idx < TILE_N * F_IN / 4; idx += 256) {
        const int nl = idx % TILE_N;
        const int k4 = idx / TILE_N;
        const int ng = nb + nl;
        float4 v = make_float4(0.f, 0.f, 0.f, 0.f);
        if (ng < n) {
            if (XDYN && isbf) {
                const ushort4 u = *(const ushort4*)((const unsigned short*)x +
                                                    (size_t)ng * F_IN + 4 * k4);
                v = make_float4(bf2f(u.x), bf2f(u.y), bf2f(u.z), bf2f(u.w));
            } else {
                v = *(const float4*)((const float*)x + (size_t)ng * F_IN + 4 * k4);
            }
        }
        xs[(4 * k4 + 0) * TILE_N + nl] = v.x;
        xs[(4 * k4 + 1) * TILE_N + nl] = v.y;
        xs[(4 * k4 + 2) * TILE_N + nl] = v.z;
        xs[(4 * k4 + 3) * TILE_N + nl] = v.w;
    }
    __syncthreads();

    const int h = t % (F_OUT / 4);              // f group: f = 4h..4h+3
    const int g = t / (F_OUT / 4);              // node group: n = nb+4g..nb+4g+3

    float4 acc0 = make_float4(0.f, 0.f, 0.f, 0.f);
    float4 acc1 = acc0, acc2 = acc0, acc3 = acc0;

#pragma unroll 8
    for (int k = 0; k < F_IN; ++k) {
        const float4 wv = *(const float4*)(Ws + k * F_OUT + 4 * h);
        const float4 xv = *(const float4*)(xs + k * TILE_N + 4 * g);
        acc0.x = fmaf(xv.x, wv.x, acc0.x); acc0.y = fmaf(xv.x, wv.y, acc0.y);
        acc0.z = fmaf(xv.x, wv.z, acc0.z); acc0.w = fmaf(xv.x, wv.w, acc0.w);
        acc1.x = fmaf(xv.y, wv.x, acc1.x); acc1.y = fmaf(xv.y, wv.y, acc1.y);
        acc1.z = fmaf(xv.y, wv.z, acc1.z); acc1.w = fmaf(xv.y, wv.w, acc1.w);
        acc2.x = fmaf(xv.z, wv.x, acc2.x); acc2.y = fmaf(xv.z, wv.y, acc2.y);
        acc2.z = fmaf(xv.z, wv.z, acc2.z); acc2.w = fmaf(xv.z, wv.w, acc2.w);
        acc3.x = fmaf(xv.w, wv.x, acc3.x); acc3.y = fmaf(xv.w, wv.y, acc3.y);
        acc3.z = fmaf(xv.w, wv.z, acc3.z); acc3.w = fmaf(xv.w, wv.w, acc3.w);
    }

    float4 accs[4] = {acc0, acc1, acc2, acc3};
#pragma unroll
    for (int i = 0; i < 4; ++i) {
        const int ng = nb + 4 * g + i;
        if (ng < n) {
            const float s = dinv[ng];
            float4 r = accs[i];
            r.x *= s; r.y *= s; r.z *= s; r.w *= s;
            *(float4*)(y + (size_t)ng * F_OUT + 4 * h) = r;
        }
    }
}

// ---------- aggregate + fused epilogue ----------
// out[c,f] = relu(dinv[c] * (sum_{r in csr[c]} y[r,f] + y[c,f]) + b[f])
template<int F>
__global__ void __launch_bounds__(256) aggregate(const float* __restrict__ y,
                                                 const int* __restrict__ csr,
                                                 const int* __restrict__ rowptr,
                                                 const int* __restrict__ cnt,
                                                 const float* __restrict__ dinv,
                                                 const void* __restrict__ b,
                                                 float* __restrict__ out, int n,
                                                 const int* __restrict__ flag) {
    const int isbf = *flag;
    constexpr int GP = 64 / F;
    const int lane = threadIdx.x & 63;
    const int sub  = lane / F;
    const int f    = lane % F;
    const int wave = (blockIdx.x * 256 + threadIdx.x) >> 6;
    const int node = wave * GP + sub;
    if (node >= n) return;

    const int beg = rowptr[node];
    const int deg = cnt[node];
    float acc = 0.f;
    int j = 0;
    for (; j + 4 <= deg; j += 4) {
        const int s0 = csr[beg + j + 0];
        const int s1 = csr[beg + j + 1];
        const int s2 = csr[beg + j + 2];
        const int s3 = csr[beg + j + 3];
        const float v0 = y[(size_t)s0 * F + f];
        const float v1 = y[(size_t)s1 * F + f];
        const float v2 = y[(size_t)s2 * F + f];
        const float v3 = y[(size_t)s3 * F + f];
        acc += (v0 + v1) + (v2 + v3);
    }
    for (; j < deg; ++j) acc += y[(size_t)csr[beg + j] * F + f];

    const float v = dinv[node] * (acc + y[(size_t)node * F + f]) + gload(b, f, isbf);
    out[(size_t)node * F + f] = fmaxf(v, 0.f);
}

// ---------- dense head: out = relu(concat(f1,f2,f3) @ Wfc + bfc) ----------
// Thread = (node, h): 4 outputs f=4h..4h+3; float4 x loads, b128 W reads.
__global__ void __launch_bounds__(256) head_kernel(const float* __restrict__ f1,
                                                   const float* __restrict__ f2,
                                                   const float* __restrict__ f3,
                                                   const void* __restrict__ Wfc,
                                                   const void* __restrict__ bfc,
                                                   void* __restrict__ out, int n,
                                                   const int* __restrict__ flag) {
    const int isbf = *flag;
    __shared__ float Ws[112 * 16];
    for (int i = threadIdx.x; i < 112 * 16; i += 256) Ws[i] = gload(Wfc, i, isbf);
    __syncthreads();

    const int h    = threadIdx.x & 3;               // f = 4h..4h+3
    const int node = blockIdx.x * 64 + (threadIdx.x >> 2);
    if (node >= n) return;

    float4 acc = make_float4(gload(bfc, 4 * h + 0, isbf), gload(bfc, 4 * h + 1, isbf),
                             gload(bfc, 4 * h + 2, isbf), gload(bfc, 4 * h + 3, isbf));

    const float* x1 = f1 + (size_t)node * 64;
#pragma unroll
    for (int k4 = 0; k4 < 16; ++k4) {
        const float4 xv = *(const float4*)(x1 + 4 * k4);
        const float xa[4] = {xv.x, xv.y, xv.z, xv.w};
#pragma unroll
        for (int j = 0; j < 4; ++j) {
            const float4 wv = *(const float4*)(Ws + (4 * k4 + j) * 16 + 4 * h);
            acc.x = fmaf(xa[j], wv.x, acc.x); acc.y = fmaf(xa[j], wv.y, acc.y);
            acc.z = fmaf(xa[j], wv.z, acc.z); acc.w = fmaf(xa[j], wv.w, acc.w);
        }
    }
    const float* x2 = f2 + (size_t)node * 32;
#pragma unroll
    for (int k4 = 0; k4 < 8; ++k4) {
        const float4 xv = *(const float4*)(x2 + 4 * k4);
        const float xa[4] = {xv.x, xv.y, xv.z, xv.w};
#pragma unroll
        for (int j = 0; j < 4; ++j) {
            const float4 wv = *(const float4*)(Ws + (64 + 4 * k4 + j) * 16 + 4 * h);
            acc.x = fmaf(xa[j], wv.x, acc.x); acc.y = fmaf(xa[j], wv.y, acc.y);
            acc.z = fmaf(xa[j], wv.z, acc.z); acc.w = fmaf(xa[j], wv.w, acc.w);
        }
    }
    const float* x3 = f3 + (size_t)node * 16;
#pragma unroll
    for (int k4 = 0; k4 < 4; ++k4) {
        const float4 xv = *(const float4*)(x3 + 4 * k4);
        const float xa[4] = {xv.x, xv.y, xv.z, xv.w};
#pragma unroll
        for (int j = 0; j < 4; ++j) {
            const float4 wv = *(const float4*)(Ws + (96 + 4 * k4 + j) * 16 + 4 * h);
            acc.x = fmaf(xa[j], wv.x, acc.x); acc.y = fmaf(xa[j], wv.y, acc.y);
            acc.z = fmaf(xa[j], wv.z, acc.z); acc.w = fmaf(xa[j], wv.w, acc.w);
        }
    }

    const float4 r = make_float4(fmaxf(acc.x, 0.f), fmaxf(acc.y, 0.f),
                                 fmaxf(acc.z, 0.f), fmaxf(acc.w, 0.f));
    const size_t o = (size_t)node * 16 + 4 * h;
    if (isbf) {
        ushort4 u;
        u.x = __hip_bfloat16_raw(__float2bfloat16(r.x)).x;
        u.y = __hip_bfloat16_raw(__float2bfloat16(r.y)).x;
        u.z = __hip_bfloat16_raw(__float2bfloat16(r.z)).x;
        u.w = __hip_bfloat16_raw(__float2bfloat16(r.w)).x;
        *(ushort4*)((unsigned short*)out + o) = u;
    } else {
        *(float4*)((float*)out + o) = r;
    }
}

// ---------- launch ----------
extern "C" void kernel_launch(void* const* d_in, const int* in_sizes, int n_in,
                              void* d_out, int out_size, void* d_ws, size_t ws_size,
                              hipStream_t stream) {
    const int*  edges = (const int*)d_in[0];
    const void* feat  = d_in[1];
    const void* W1    = d_in[2];
    const void* b1    = d_in[3];
    const void* W2    = d_in[4];
    const void* b2    = d_in[5];
    const void* W3    = d_in[6];
    const void* b3    = d_in[7];
    const void* Wfc   = d_in[8];
    const void* bfc   = d_in[9];

    const int E = in_sizes[0] / 2;
    const int N = in_sizes[1] / 128;
    const int* row = edges;
    const int* col = edges + E;

    // workspace (~85 MB):
    // flag | dinv[N] | cnt[N] | cursor[N] | rowptr[N] | csr[E] | y[64N] | f1[64N] | f2[32N] | f3[16N] | bsum
    char* p = (char*)d_ws;
    int*   flag   = (int*)p;              p += 16;
    float* dinv   = (float*)p;            p += (size_t)N * 4;
    int*   cnt    = (int*)p;              p += (size_t)N * 4;
    int*   cursor = (int*)p;              p += (size_t)N * 4;
    int*   rowptr = (int*)p;              p += (size_t)N * 4;
    int*   csr    = (int*)p;              p += (size_t)E * 4;
    float* y      = (float*)p;            p += (size_t)N * 64 * 4;
    float* f1     = (float*)p;            p += (size_t)N * 64 * 4;
    float* f2     = (float*)p;            p += (size_t)N * 32 * 4;
    float* f3     = (float*)p;            p += (size_t)N * 16 * 4;
    int*   bsum   = (int*)p;              // DIVUP(N,1024) ints

    detect_dtype<<<1, 256, 0, stream>>>(feat, flag);

    // degrees + norm
    hipMemsetAsync(cnt, 0, (size_t)N * sizeof(int), stream);
    hipMemsetAsync(cursor, 0, (size_t)N * sizeof(int), stream);
    count_deg<<<DIVUP(E, 256), 256, 0, stream>>>(col, cnt, E);
    make_dinv<<<DIVUP(N, 256), 256, 0, stream>>>(cnt, dinv, N);

    // CSR build
    const int nb = DIVUP(N, 1024);
    scan_block_sums<<<nb, 256, 0, stream>>>(cnt, bsum, N);
    scan_bsum<<<1, 256, 0, stream>>>(bsum, nb);
    scan_final<<<nb, 256, 0, stream>>>(cnt, bsum, rowptr, N);
    csr_fill<<<DIVUP(E, 256), 256, 0, stream>>>(row, col, rowptr, cursor, csr, E);

    // layer 1: 128 -> 64  (TILE_N = 64)
    gemm_tile<128, 64, true><<<DIVUP(N, 64), 256, 0, stream>>>(feat, W1, dinv, y, N, flag);
    aggregate<64><<<DIVUP(N, 4), 256, 0, stream>>>(y, csr, rowptr, cnt, dinv, b1, f1, N, flag);

    // layer 2: 64 -> 32  (TILE_N = 128)
    gemm_tile<64, 32, false><<<DIVUP(N, 128), 256, 0, stream>>>(f1, W2, dinv, y, N, flag);
    aggregate<32><<<DIVUP(N, 8), 256, 0, stream>>>(y, csr, rowptr, cnt, dinv, b2, f2, N, flag);

    // layer 3: 32 -> 16  (TILE_N = 256)
    gemm_tile<32, 16, false><<<DIVUP(N, 256), 256, 0, stream>>>(f2, W3, dinv, y, N, flag);
    aggregate<16><<<DIVUP(N, 16), 256, 0, stream>>>(y, csr, rowptr, cnt, dinv, b3, f3, N, flag);

    // dense head
    head_kernel<<<DIVUP(N, 64), 256, 0, stream>>>(f1, f2, f3, Wfc, bfc, d_out, N, flag);
}

// Round 5
// 711.804 us; speedup vs baseline: 3.0998x; 1.1233x over previous
//
#include <hip/hip_runtime.h>
#include <hip/hip_bf16.h>

#define DIVUP(a, b) (((a) + (b) - 1) / (b))

// ---------- helpers ----------
__device__ __forceinline__ float bf2f(unsigned short u) {
    union { unsigned int i; float f; } v;
    v.i = ((unsigned int)u) << 16;
    return v.f;
}
__device__ __forceinline__ unsigned short f2bfu(float x) {
    return __hip_bfloat16_raw(__float2bfloat16(x)).x;   // RNE
}

// dtype-adaptive scalar load: isbf=1 -> bf16, isbf=0 -> f32
__device__ __forceinline__ float gload(const void* p, int i, int isbf) {
    return isbf ? bf2f(((const unsigned short*)p)[i]) : ((const float*)p)[i];
}

// ---------- dtype detection ----------
// Features ~ N(0,1). bf16 buffer: even-indexed bf16 elements are N(0,1) samples
// (~100% of |v| in [1e-4,10]). f32 buffer: even bf16 indices are low mantissa
// halves -> random exponent, ~7% in range. flag=1 means bf16.
__global__ void __launch_bounds__(256) detect_dtype(const void* __restrict__ feat,
                                                    int* __restrict__ flag) {
    __shared__ int cnt;
    if (threadIdx.x == 0) cnt = 0;
    __syncthreads();
    const unsigned short* u = (const unsigned short*)feat;
    int c = 0;
#pragma unroll
    for (int rep = 0; rep < 4; ++rep) {
        const int idx = threadIdx.x * 2 + rep * 512;
        const float v = fabsf(bf2f(u[idx]));
        c += (v > 1e-4f && v < 10.0f) ? 1 : 0;
    }
    atomicAdd(&cnt, c);
    __syncthreads();
    if (threadIdx.x == 0) *flag = (cnt > 512) ? 1 : 0;
}

// ---------- degree count (int) ----------
__global__ void __launch_bounds__(256) count_deg(const int* __restrict__ col,
                                                 int* __restrict__ cnt, int nE) {
    int e = blockIdx.x * 256 + threadIdx.x;
    if (e < nE) atomicAdd(&cnt[col[e]], 1);
}

__global__ void __launch_bounds__(256) make_dinv(const int* __restrict__ cnt,
                                                 float* __restrict__ dinv, int n) {
    int i = blockIdx.x * 256 + threadIdx.x;
    if (i < n) dinv[i] = rsqrtf((float)cnt[i] + 1.0f);   // +1 self-loop
}

// ---------- exclusive scan of cnt[N] -> rowptr[N] (3-phase) ----------
__global__ void __launch_bounds__(256) scan_block_sums(const int* __restrict__ cnt,
                                                       int* __restrict__ bsum, int n) {
    __shared__ int red[256];
    const int base = blockIdx.x * 1024;
    int s = 0;
    for (int i = threadIdx.x; i < 1024; i += 256) {
        const int idx = base + i;
        s += (idx < n) ? cnt[idx] : 0;
    }
    red[threadIdx.x] = s;
    __syncthreads();
    for (int off = 128; off > 0; off >>= 1) {
        if (threadIdx.x < off) red[threadIdx.x] += red[threadIdx.x + off];
        __syncthreads();
    }
    if (threadIdx.x == 0) bsum[blockIdx.x] = red[0];
}

__global__ void __launch_bounds__(256) scan_bsum(int* __restrict__ bsum, int nb) {
    __shared__ int tmp[256];
    const int x = threadIdx.x;
    const int v = (x < nb) ? bsum[x] : 0;
    tmp[x] = v;
    __syncthreads();
    int val = v;
    for (int off = 1; off < 256; off <<= 1) {
        const int t = (x >= off) ? tmp[x - off] : 0;
        __syncthreads();
        val += t;
        tmp[x] = val;
        __syncthreads();
    }
    if (x < nb) bsum[x] = val - v;   // exclusive
}

__global__ void __launch_bounds__(256) scan_final(const int* __restrict__ cnt,
                                                  const int* __restrict__ bsum,
                                                  int* __restrict__ rowptr, int n) {
    __shared__ int tsum[256];
    const int base = blockIdx.x * 1024;
    const int x = threadIdx.x;
    int v[4];
    int s = 0;
#pragma unroll
    for (int k = 0; k < 4; ++k) {
        const int idx = base + x * 4 + k;
        v[k] = (idx < n) ? cnt[idx] : 0;
        s += v[k];
    }
    tsum[x] = s;
    __syncthreads();
    int val = s;
    for (int off = 1; off < 256; off <<= 1) {
        const int t = (x >= off) ? tsum[x - off] : 0;
        __syncthreads();
        val += t;
        tsum[x] = val;
        __syncthreads();
    }
    int prefix = bsum[blockIdx.x] + (val - s);
#pragma unroll
    for (int k = 0; k < 4; ++k) {
        const int idx = base + x * 4 + k;
        if (idx < n) rowptr[idx] = prefix;
        prefix += v[k];
    }
}

// ---------- CSR fill, range-partitioned ----------
// 4 sub-passes over edges inside one launch; pass r handles cols in
// [r*rsize, (r+1)*rsize). Active region (csr slice 3.2MB + cursors 100KB)
// fits per-XCD 4MB L2 -> 4B stores accumulate into lines before writeback
// (round-4 counters: unpartitioned fill wrote 197MB HBM for 12.8MB useful).
// Entry is premultiplied: row*128 = byte offset into bf16 y for F=64;
// layer F=32 shifts >>1, F=16 shifts >>2.
__global__ void __launch_bounds__(256) csr_fill_ranged(const int* __restrict__ row,
                                                       const int* __restrict__ col,
                                                       const int* __restrict__ rowptr,
                                                       int* __restrict__ cursor,
                                                       int* __restrict__ csr,
                                                       int nE, int nbE, int rsize) {
    const int range = blockIdx.x / nbE;
    const int e = (blockIdx.x - range * nbE) * 256 + threadIdx.x;
    if (e >= nE) return;
    const int c = col[e];
    const unsigned int rel = (unsigned int)(c - range * rsize);
    if (rel < (unsigned int)rsize) {
        const int p = atomicAdd(&cursor[c], 1);
        csr[rowptr[c] + p] = row[e] << 7;
    }
}

// ---------- register-tiled GEMM: y = bf16((x @ W) * dinv[node]) ----------
// Block: 256 threads. Thread tile = 4 nodes x 4 f. TILE_N = 4096/F_OUT.
template<int F_IN, int F_OUT, bool XDYN>
__global__ void __launch_bounds__(256) gemm_tile(const void* __restrict__ x,
                                                 const void* __restrict__ W,
                                                 const float* __restrict__ dinv,
                                                 unsigned short* __restrict__ y, int n,
                                                 const int* __restrict__ flag) {
    constexpr int TILE_N = 4096 / F_OUT;        // 64 / 128 / 256
    const int isbf = *flag;
    __shared__ float Ws[F_IN * F_OUT];
    __shared__ float xs[F_IN * TILE_N];

    const int t = threadIdx.x;
    for (int i = t; i < F_IN * F_OUT; i += 256) Ws[i] = gload(W, i, isbf);

    const int nb = blockIdx.x * TILE_N;
    for (int idx = t; idx < TILE_N * F_IN / 4; idx += 256) {
        const int nl = idx % TILE_N;
        const int k4 = idx / TILE_N;
        const int ng = nb + nl;
        float4 v = make_float4(0.f, 0.f, 0.f, 0.f);
        if (ng < n) {
            if (XDYN && isbf) {
                const ushort4 u = *(const ushort4*)((const unsigned short*)x +
                                                    (size_t)ng * F_IN + 4 * k4);
                v = make_float4(bf2f(u.x), bf2f(u.y), bf2f(u.z), bf2f(u.w));
            } else {
                v = *(const float4*)((const float*)x + (size_t)ng * F_IN + 4 * k4);
            }
        }
        xs[(4 * k4 + 0) * TILE_N + nl] = v.x;
        xs[(4 * k4 + 1) * TILE_N + nl] = v.y;
        xs[(4 * k4 + 2) * TILE_N + nl] = v.z;
        xs[(4 * k4 + 3) * TILE_N + nl] = v.w;
    }
    __syncthreads();

    const int h = t % (F_OUT / 4);
    const int g = t / (F_OUT / 4);

    float4 acc0 = make_float4(0.f, 0.f, 0.f, 0.f);
    float4 acc1 = acc0, acc2 = acc0, acc3 = acc0;

#pragma unroll 8
    for (int k = 0; k < F_IN; ++k) {
        const float4 wv = *(const float4*)(Ws + k * F_OUT + 4 * h);
        const float4 xv = *(const float4*)(xs + k * TILE_N + 4 * g);
        acc0.x = fmaf(xv.x, wv.x, acc0.x); acc0.y = fmaf(xv.x, wv.y, acc0.y);
        acc0.z = fmaf(xv.x, wv.z, acc0.z); acc0.w = fmaf(xv.x, wv.w, acc0.w);
        acc1.x = fmaf(xv.y, wv.x, acc1.x); acc1.y = fmaf(xv.y, wv.y, acc1.y);
        acc1.z = fmaf(xv.y, wv.z, acc1.z); acc1.w = fmaf(xv.y, wv.w, acc1.w);
        acc2.x = fmaf(xv.z, wv.x, acc2.x); acc2.y = fmaf(xv.z, wv.y, acc2.y);
        acc2.z = fmaf(xv.z, wv.z, acc2.z); acc2.w = fmaf(xv.z, wv.w, acc2.w);
        acc3.x = fmaf(xv.w, wv.x, acc3.x); acc3.y = fmaf(xv.w, wv.y, acc3.y);
        acc3.z = fmaf(xv.w, wv.z, acc3.z); acc3.w = fmaf(xv.w, wv.w, acc3.w);
    }

    float4 accs[4] = {acc0, acc1, acc2, acc3};
#pragma unroll
    for (int i = 0; i < 4; ++i) {
        const int ng = nb + 4 * g + i;
        if (ng < n) {
            const float s = dinv[ng];
            const float4 r = accs[i];
            ushort4 u;
            u.x = f2bfu(r.x * s); u.y = f2bfu(r.y * s);
            u.z = f2bfu(r.z * s); u.w = f2bfu(r.w * s);
            *(ushort4*)(y + (size_t)ng * F_OUT + 4 * h) = u;
        }
    }
}

// ---------- aggregate + fused epilogue ----------
// out[c,f] = relu(dinv[c] * (sum_{r in csr[c]} y[r,f] + y[c,f]) + b[f])
// csr entries are premultiplied byte offsets (row*128); shift per layer.
template<int F>
__global__ void __launch_bounds__(256) aggregate(const unsigned short* __restrict__ y,
                                                 const int* __restrict__ csr,
                                                 const int* __restrict__ rowptr,
                                                 const int* __restrict__ cnt,
                                                 const float* __restrict__ dinv,
                                                 const void* __restrict__ b,
                                                 float* __restrict__ out, int n,
                                                 const int* __restrict__ flag) {
    const int isbf = *flag;
    constexpr int GP = 64 / F;
    constexpr int SH = (F == 64) ? 0 : (F == 32) ? 1 : 2;
    const int lane = threadIdx.x & 63;
    const int sub  = lane / F;
    const int f    = lane % F;
    const int wave = (blockIdx.x * 256 + threadIdx.x) >> 6;
    const int node = wave * GP + sub;
    if (node >= n) return;

    const int beg = rowptr[node];
    const int deg = cnt[node];
    const char* yb = (const char*)y;
    const int f2 = f * 2;
    float acc = 0.f;
    int j = 0;
    for (; j + 4 <= deg; j += 4) {
        const int o0 = csr[beg + j + 0] >> SH;
        const int o1 = csr[beg + j + 1] >> SH;
        const int o2 = csr[beg + j + 2] >> SH;
        const int o3 = csr[beg + j + 3] >> SH;
        const float v0 = bf2f(*(const unsigned short*)(yb + o0 + f2));
        const float v1 = bf2f(*(const unsigned short*)(yb + o1 + f2));
        const float v2 = bf2f(*(const unsigned short*)(yb + o2 + f2));
        const float v3 = bf2f(*(const unsigned short*)(yb + o3 + f2));
        acc += (v0 + v1) + (v2 + v3);
    }
    for (; j < deg; ++j)
        acc += bf2f(*(const unsigned short*)(yb + (csr[beg + j] >> SH) + f2));

    const float self = bf2f(y[(size_t)node * F + f]);
    const float v = dinv[node] * (acc + self) + gload(b, f, isbf);
    out[(size_t)node * F + f] = fmaxf(v, 0.f);
}

// ---------- dense head: out = relu(concat(f1,f2,f3) @ Wfc + bfc) ----------
__global__ void __launch_bounds__(256) head_kernel(const float* __restrict__ f1,
                                                   const float* __restrict__ f2,
                                                   const float* __restrict__ f3,
                                                   const void* __restrict__ Wfc,
                                                   const void* __restrict__ bfc,
                                                   void* __restrict__ out, int n,
                                                   const int* __restrict__ flag) {
    const int isbf = *flag;
    __shared__ float Ws[112 * 16];
    for (int i = threadIdx.x; i < 112 * 16; i += 256) Ws[i] = gload(Wfc, i, isbf);
    __syncthreads();

    const int h    = threadIdx.x & 3;
    const int node = blockIdx.x * 64 + (threadIdx.x >> 2);
    if (node >= n) return;

    float4 acc = make_float4(gload(bfc, 4 * h + 0, isbf), gload(bfc, 4 * h + 1, isbf),
                             gload(bfc, 4 * h + 2, isbf), gload(bfc, 4 * h + 3, isbf));

    const float* x1 = f1 + (size_t)node * 64;
#pragma unroll
    for (int k4 = 0; k4 < 16; ++k4) {
        const float4 xv = *(const float4*)(x1 + 4 * k4);
        const float xa[4] = {xv.x, xv.y, xv.z, xv.w};
#pragma unroll
        for (int j = 0; j < 4; ++j) {
            const float4 wv = *(const float4*)(Ws + (4 * k4 + j) * 16 + 4 * h);
            acc.x = fmaf(xa[j], wv.x, acc.x); acc.y = fmaf(xa[j], wv.y, acc.y);
            acc.z = fmaf(xa[j], wv.z, acc.z); acc.w = fmaf(xa[j], wv.w, acc.w);
        }
    }
    const float* x2 = f2 + (size_t)node * 32;
#pragma unroll
    for (int k4 = 0; k4 < 8; ++k4) {
        const float4 xv = *(const float4*)(x2 + 4 * k4);
        const float xa[4] = {xv.x, xv.y, xv.z, xv.w};
#pragma unroll
        for (int j = 0; j < 4; ++j) {
            const float4 wv = *(const float4*)(Ws + (64 + 4 * k4 + j) * 16 + 4 * h);
            acc.x = fmaf(xa[j], wv.x, acc.x); acc.y = fmaf(xa[j], wv.y, acc.y);
            acc.z = fmaf(xa[j], wv.z, acc.z); acc.w = fmaf(xa[j], wv.w, acc.w);
        }
    }
    const float* x3 = f3 + (size_t)node * 16;
#pragma unroll
    for (int k4 = 0; k4 < 4; ++k4) {
        const float4 xv = *(const float4*)(x3 + 4 * k4);
        const float xa[4] = {xv.x, xv.y, xv.z, xv.w};
#pragma unroll
        for (int j = 0; j < 4; ++j) {
            const float4 wv = *(const float4*)(Ws + (96 + 4 * k4 + j) * 16 + 4 * h);
            acc.x = fmaf(xa[j], wv.x, acc.x); acc.y = fmaf(xa[j], wv.y, acc.y);
            acc.z = fmaf(xa[j], wv.z, acc.z); acc.w = fmaf(xa[j], wv.w, acc.w);
        }
    }

    const float4 r = make_float4(fmaxf(acc.x, 0.f), fmaxf(acc.y, 0.f),
                                 fmaxf(acc.z, 0.f), fmaxf(acc.w, 0.f));
    const size_t o = (size_t)node * 16 + 4 * h;
    if (isbf) {
        ushort4 u;
        u.x = f2bfu(r.x); u.y = f2bfu(r.y); u.z = f2bfu(r.z); u.w = f2bfu(r.w);
        *(ushort4*)((unsigned short*)out + o) = u;
    } else {
        *(float4*)((float*)out + o) = r;
    }
}

// ---------- launch ----------
extern "C" void kernel_launch(void* const* d_in, const int* in_sizes, int n_in,
                              void* d_out, int out_size, void* d_ws, size_t ws_size,
                              hipStream_t stream) {
    const int*  edges = (const int*)d_in[0];
    const void* feat  = d_in[1];
    const void* W1    = d_in[2];
    const void* b1    = d_in[3];
    const void* W2    = d_in[4];
    const void* b2    = d_in[5];
    const void* W3    = d_in[6];
    const void* b3    = d_in[7];
    const void* Wfc   = d_in[8];
    const void* bfc   = d_in[9];

    const int E = in_sizes[0] / 2;
    const int N = in_sizes[1] / 128;
    const int* row = edges;
    const int* col = edges + E;

    // workspace (~73 MB):
    // flag | dinv[N] | cnt[N] | cursor[N] | rowptr[N] | csr[E] | y:bf16[64N] |
    // f1[64N] f32 | f2[32N] f32 | f3[16N] f32 | bsum
    char* p = (char*)d_ws;
    int*   flag   = (int*)p;              p += 16;
    float* dinv   = (float*)p;            p += (size_t)N * 4;
    int*   cnt    = (int*)p;              p += (size_t)N * 4;
    int*   cursor = (int*)p;              p += (size_t)N * 4;
    int*   rowptr = (int*)p;              p += (size_t)N * 4;
    int*   csr    = (int*)p;              p += (size_t)E * 4;
    unsigned short* y = (unsigned short*)p; p += (size_t)N * 64 * 2;
    float* f1     = (float*)p;            p += (size_t)N * 64 * 4;
    float* f2     = (float*)p;            p += (size_t)N * 32 * 4;
    float* f3     = (float*)p;            p += (size_t)N * 16 * 4;
    int*   bsum   = (int*)p;

    detect_dtype<<<1, 256, 0, stream>>>(feat, flag);

    // degrees + norm
    hipMemsetAsync(cnt, 0, (size_t)N * sizeof(int), stream);
    hipMemsetAsync(cursor, 0, (size_t)N * sizeof(int), stream);
    count_deg<<<DIVUP(E, 256), 256, 0, stream>>>(col, cnt, E);
    make_dinv<<<DIVUP(N, 256), 256, 0, stream>>>(cnt, dinv, N);

    // CSR build
    const int nb = DIVUP(N, 1024);
    scan_block_sums<<<nb, 256, 0, stream>>>(cnt, bsum, N);
    scan_bsum<<<1, 256, 0, stream>>>(bsum, nb);
    scan_final<<<nb, 256, 0, stream>>>(cnt, bsum, rowptr, N);
    const int nbE = DIVUP(E, 256);
    csr_fill_ranged<<<nbE * 4, 256, 0, stream>>>(row, col, rowptr, cursor, csr,
                                                 E, nbE, DIVUP(N, 4));

    // layer 1: 128 -> 64  (TILE_N = 64)
    gemm_tile<128, 64, true><<<DIVUP(N, 64), 256, 0, stream>>>(feat, W1, dinv, y, N, flag);
    aggregate<64><<<DIVUP(N, 4), 256, 0, stream>>>(y, csr, rowptr, cnt, dinv, b1, f1, N, flag);

    // layer 2: 64 -> 32  (TILE_N = 128)
    gemm_tile<64, 32, false><<<DIVUP(N, 128), 256, 0, stream>>>(f1, W2, dinv, y, N, flag);
    aggregate<32><<<DIVUP(N, 8), 256, 0, stream>>>(y, csr, rowptr, cnt, dinv, b2, f2, N, flag);

    // layer 3: 32 -> 16  (TILE_N = 256)
    gemm_tile<32, 16, false><<<DIVUP(N, 256), 256, 0, stream>>>(f2, W3, dinv, y, N, flag);
    aggregate<16><<<DIVUP(N, 16), 256, 0, stream>>>(y, csr, rowptr, cnt, dinv, b3, f3, N, flag);

    // dense head
    head_kernel<<<DIVUP(N, 64), 256, 0, stream>>>(f1, f2, f3, Wfc, bfc, d_out, N, flag);
}

// Round 6
// 519.873 us; speedup vs baseline: 4.2442x; 1.3692x over previous
//
#include <hip/hip_runtime.h>
#include <hip/hip_bf16.h>

#define DIVUP(a, b) (((a) + (b) - 1) / (b))

// ---------- helpers ----------
__device__ __forceinline__ float bf2f(unsigned short u) {
    union { unsigned int i; float f; } v;
    v.i = ((unsigned int)u) << 16;
    return v.f;
}
__device__ __forceinline__ unsigned short f2bfu(float x) {
    return __hip_bfloat16_raw(__float2bfloat16(x)).x;   // RNE
}
__device__ __forceinline__ float gload(const void* p, int i, int isbf) {
    return isbf ? bf2f(((const unsigned short*)p)[i]) : ((const float*)p)[i];
}

// ---------- dtype detection (see round-1 note; f32 vs bf16 inputs) ----------
__global__ void __launch_bounds__(256) detect_dtype(const void* __restrict__ feat,
                                                    int* __restrict__ flag) {
    __shared__ int cnt;
    if (threadIdx.x == 0) cnt = 0;
    __syncthreads();
    const unsigned short* u = (const unsigned short*)feat;
    int c = 0;
#pragma unroll
    for (int rep = 0; rep < 4; ++rep) {
        const int idx = threadIdx.x * 2 + rep * 512;
        const float v = fabsf(bf2f(u[idx]));
        c += (v > 1e-4f && v < 10.0f) ? 1 : 0;
    }
    atomicAdd(&cnt, c);
    __syncthreads();
    if (threadIdx.x == 0) *flag = (cnt > 512) ? 1 : 0;
}

// ================= CSR build: counting sort, zero global atomics =================
// bucket = col >> 8 (256 cols per bucket). EPB = 8192 edges per phase-A block.
// cntRB[bucket*B + block] -> exclusive scan -> seg_off (bucket-major: each
// bucket's pair data contiguous). Single-owner writes everywhere: random 4B
// stores only ever come from ONE block -> one XCD L2 -> one writeback
// (round-4/5 evidence: multi-XCD random atomics+stores = 160us, BW-idle).

__global__ void __launch_bounds__(256) parta_hist(const int* __restrict__ col,
                                                  int* __restrict__ cntRB,
                                                  int E, int B, int NB) {
    __shared__ int h[512];
    for (int i = threadIdx.x; i < NB; i += 256) h[i] = 0;
    __syncthreads();
    const int base = blockIdx.x * 8192;
#pragma unroll
    for (int k = 0; k < 32; ++k) {
        const int e = base + k * 256 + threadIdx.x;
        if (e < E) atomicAdd(&h[col[e] >> 8], 1);
    }
    __syncthreads();
    for (int i = threadIdx.x; i < NB; i += 256) cntRB[i * B + blockIdx.x] = h[i];
}

// ---------- generic 3-phase exclusive scan (n <= 256*1024) ----------
__global__ void __launch_bounds__(256) scan_block_sums(const int* __restrict__ cnt,
                                                       int* __restrict__ bsum, int n) {
    __shared__ int red[256];
    const int base = blockIdx.x * 1024;
    int s = 0;
    for (int i = threadIdx.x; i < 1024; i += 256) {
        const int idx = base + i;
        s += (idx < n) ? cnt[idx] : 0;
    }
    red[threadIdx.x] = s;
    __syncthreads();
    for (int off = 128; off > 0; off >>= 1) {
        if (threadIdx.x < off) red[threadIdx.x] += red[threadIdx.x + off];
        __syncthreads();
    }
    if (threadIdx.x == 0) bsum[blockIdx.x] = red[0];
}

__global__ void __launch_bounds__(256) scan_bsum(int* __restrict__ bsum, int nb) {
    __shared__ int tmp[256];
    const int x = threadIdx.x;
    const int v = (x < nb) ? bsum[x] : 0;
    tmp[x] = v;
    __syncthreads();
    int val = v;
    for (int off = 1; off < 256; off <<= 1) {
        const int t = (x >= off) ? tmp[x - off] : 0;
        __syncthreads();
        val += t;
        tmp[x] = val;
        __syncthreads();
    }
    if (x < nb) bsum[x] = val - v;   // exclusive
}

__global__ void __launch_bounds__(256) scan_final(const int* __restrict__ cnt,
                                                  const int* __restrict__ bsum,
                                                  int* __restrict__ outp, int n) {
    __shared__ int tsum[256];
    const int base = blockIdx.x * 1024;
    const int x = threadIdx.x;
    int v[4];
    int s = 0;
#pragma unroll
    for (int k = 0; k < 4; ++k) {
        const int idx = base + x * 4 + k;
        v[k] = (idx < n) ? cnt[idx] : 0;
        s += v[k];
    }
    tsum[x] = s;
    __syncthreads();
    int val = s;
    for (int off = 1; off < 256; off <<= 1) {
        const int t = (x >= off) ? tsum[x - off] : 0;
        __syncthreads();
        val += t;
        tsum[x] = val;
        __syncthreads();
    }
    int prefix = bsum[blockIdx.x] + (val - s);
#pragma unroll
    for (int k = 0; k < 4; ++k) {
        const int idx = base + x * 4 + k;
        if (idx < n) outp[idx] = prefix;
        prefix += v[k];
    }
}

// ---------- phase A scatter: partition pairs into bucket segments ----------
__global__ void __launch_bounds__(256) parta_scatter(const int* __restrict__ row,
                                                     const int* __restrict__ col,
                                                     const int* __restrict__ seg_off,
                                                     int2* __restrict__ part,
                                                     int E, int B, int NB) {
    __shared__ int cur[512];
    for (int i = threadIdx.x; i < NB; i += 256) cur[i] = seg_off[i * B + blockIdx.x];
    __syncthreads();
    const int base = blockIdx.x * 8192;
#pragma unroll
    for (int k = 0; k < 32; ++k) {
        const int e = base + k * 256 + threadIdx.x;
        if (e < E) {
            const int c = col[e];
            const int r = row[e];
            const int p = atomicAdd(&cur[c >> 8], 1);
            part[p] = make_int2(c, r);
        }
    }
}

// ---------- phase B: per-range CSR build + degrees + dinv ----------
// Block r exclusively owns cols [r*256, r*256+256): reads its contiguous pair
// segment twice (L2-hot 2nd time), LDS count + scan -> rowptr/cnt/dinv, then
// LDS-cursor placement. csr entry = row << 7 (byte offset into bf16 y, F=64).
__global__ void __launch_bounds__(256) csr_build(const int2* __restrict__ part,
                                                 const int* __restrict__ seg_off,
                                                 int* __restrict__ rowptr,
                                                 int* __restrict__ cnt,
                                                 float* __restrict__ dinv,
                                                 int* __restrict__ csr,
                                                 int E, int B, int NB, int N) {
    __shared__ int cl[256];
    __shared__ int sc[256];
    const int r  = blockIdx.x;
    const int c0 = r << 8;
    const int s0 = seg_off[r * B];
    const int s1 = (r == NB - 1) ? E : seg_off[(r + 1) * B];
    cl[threadIdx.x] = 0;
    __syncthreads();
    for (int i = s0 + threadIdx.x; i < s1; i += 256)
        atomicAdd(&cl[part[i].x - c0], 1);
    __syncthreads();
    const int v = cl[threadIdx.x];
    sc[threadIdx.x] = v;
    __syncthreads();
    int val = v;
    for (int off = 1; off < 256; off <<= 1) {
        const int t = (threadIdx.x >= off) ? sc[threadIdx.x - off] : 0;
        __syncthreads();
        val += t;
        sc[threadIdx.x] = val;
        __syncthreads();
    }
    const int excl = val - v;
    const int c = c0 + threadIdx.x;
    if (c < N) {
        rowptr[c] = s0 + excl;
        cnt[c]    = v;
        dinv[c]   = rsqrtf((float)v + 1.0f);
    }
    cl[threadIdx.x] = s0 + excl;   // reuse as cursor
    __syncthreads();
    for (int i = s0 + threadIdx.x; i < s1; i += 256) {
        const int2 pr = part[i];
        const int p = atomicAdd(&cl[pr.x - c0], 1);
        csr[p] = pr.y << 7;
    }
}

// ================= layers =================

// register-tiled GEMM: y = bf16((x @ W) * dinv[node])
// XMODE: 0 = x dtype per flag (layer 1 raw input), 1 = x is bf16 (internal).
template<int F_IN, int F_OUT, int XMODE>
__global__ void __launch_bounds__(256) gemm_tile(const void* __restrict__ x,
                                                 const void* __restrict__ W,
                                                 const float* __restrict__ dinv,
                                                 unsigned short* __restrict__ y, int n,
                                                 const int* __restrict__ flag) {
    constexpr int TILE_N = 4096 / F_OUT;        // 64 / 128 / 256
    const int isbf = *flag;
    __shared__ float Ws[F_IN * F_OUT];
    __shared__ float xs[F_IN * TILE_N];

    const int t = threadIdx.x;
    for (int i = t; i < F_IN * F_OUT; i += 256) Ws[i] = gload(W, i, isbf);

    const int nb = blockIdx.x * TILE_N;
    for (int idx = t; idx < TILE_N * F_IN / 4; idx += 256) {
        const int nl = idx % TILE_N;
        const int k4 = idx / TILE_N;
        const int ng = nb + nl;
        float4 v = make_float4(0.f, 0.f, 0.f, 0.f);
        if (ng < n) {
            if (XMODE == 1 || isbf) {
                const ushort4 u = *(const ushort4*)((const unsigned short*)x +
                                                    (size_t)ng * F_IN + 4 * k4);
                v = make_float4(bf2f(u.x), bf2f(u.y), bf2f(u.z), bf2f(u.w));
            } else {
                v = *(const float4*)((const float*)x + (size_t)ng * F_IN + 4 * k4);
            }
        }
        xs[(4 * k4 + 0) * TILE_N + nl] = v.x;
        xs[(4 * k4 + 1) * TILE_N + nl] = v.y;
        xs[(4 * k4 + 2) * TILE_N + nl] = v.z;
        xs[(4 * k4 + 3) * TILE_N + nl] = v.w;
    }
    __syncthreads();

    const int h = t % (F_OUT / 4);
    const int g = t / (F_OUT / 4);

    float4 acc0 = make_float4(0.f, 0.f, 0.f, 0.f);
    float4 acc1 = acc0, acc2 = acc0, acc3 = acc0;

#pragma unroll 8
    for (int k = 0; k < F_IN; ++k) {
        const float4 wv = *(const float4*)(Ws + k * F_OUT + 4 * h);
        const float4 xv = *(const float4*)(xs + k * TILE_N + 4 * g);
        acc0.x = fmaf(xv.x, wv.x, acc0.x); acc0.y = fmaf(xv.x, wv.y, acc0.y);
        acc0.z = fmaf(xv.x, wv.z, acc0.z); acc0.w = fmaf(xv.x, wv.w, acc0.w);
        acc1.x = fmaf(xv.y, wv.x, acc1.x); acc1.y = fmaf(xv.y, wv.y, acc1.y);
        acc1.z = fmaf(xv.y, wv.z, acc1.z); acc1.w = fmaf(xv.y, wv.w, acc1.w);
        acc2.x = fmaf(xv.z, wv.x, acc2.x); acc2.y = fmaf(xv.z, wv.y, acc2.y);
        acc2.z = fmaf(xv.z, wv.z, acc2.z); acc2.w = fmaf(xv.z, wv.w, acc2.w);
        acc3.x = fmaf(xv.w, wv.x, acc3.x); acc3.y = fmaf(xv.w, wv.y, acc3.y);
        acc3.z = fmaf(xv.w, wv.z, acc3.z); acc3.w = fmaf(xv.w, wv.w, acc3.w);
    }

    float4 accs[4] = {acc0, acc1, acc2, acc3};
#pragma unroll
    for (int i = 0; i < 4; ++i) {
        const int ng = nb + 4 * g + i;
        if (ng < n) {
            const float s = dinv[ng];
            const float4 rr = accs[i];
            ushort4 u;
            u.x = f2bfu(rr.x * s); u.y = f2bfu(rr.y * s);
            u.z = f2bfu(rr.z * s); u.w = f2bfu(rr.w * s);
            *(ushort4*)(y + (size_t)ng * F_OUT + 4 * h) = u;
        }
    }
}

// aggregate + fused epilogue: fout = bf16(relu(dinv*(sum + self) + b))
template<int F>
__global__ void __launch_bounds__(256) aggregate(const unsigned short* __restrict__ y,
                                                 const int* __restrict__ csr,
                                                 const int* __restrict__ rowptr,
                                                 const int* __restrict__ cnt,
                                                 const float* __restrict__ dinv,
                                                 const void* __restrict__ b,
                                                 unsigned short* __restrict__ out, int n,
                                                 const int* __restrict__ flag) {
    const int isbf = *flag;
    constexpr int GP = 64 / F;
    constexpr int SH = (F == 64) ? 0 : (F == 32) ? 1 : 2;
    const int lane = threadIdx.x & 63;
    const int sub  = lane / F;
    const int f    = lane % F;
    const int wave = (blockIdx.x * 256 + threadIdx.x) >> 6;
    const int node = wave * GP + sub;
    if (node >= n) return;

    const int beg = rowptr[node];
    const int deg = cnt[node];
    const char* yb = (const char*)y;
    const int f2 = f * 2;
    float acc = 0.f;
    int j = 0;
    for (; j + 4 <= deg; j += 4) {
        const int o0 = csr[beg + j + 0] >> SH;
        const int o1 = csr[beg + j + 1] >> SH;
        const int o2 = csr[beg + j + 2] >> SH;
        const int o3 = csr[beg + j + 3] >> SH;
        const float v0 = bf2f(*(const unsigned short*)(yb + o0 + f2));
        const float v1 = bf2f(*(const unsigned short*)(yb + o1 + f2));
        const float v2 = bf2f(*(const unsigned short*)(yb + o2 + f2));
        const float v3 = bf2f(*(const unsigned short*)(yb + o3 + f2));
        acc += (v0 + v1) + (v2 + v3);
    }
    for (; j < deg; ++j)
        acc += bf2f(*(const unsigned short*)(yb + (csr[beg + j] >> SH) + f2));

    const float self = bf2f(y[(size_t)node * F + f]);
    const float v = dinv[node] * (acc + self) + gload(b, f, isbf);
    out[(size_t)node * F + f] = f2bfu(fmaxf(v, 0.f));
}

// dense head: out = relu(concat(f1,f2,f3) @ Wfc + bfc); f-buffers are bf16
__global__ void __launch_bounds__(256) head_kernel(const unsigned short* __restrict__ f1,
                                                   const unsigned short* __restrict__ f2,
                                                   const unsigned short* __restrict__ f3,
                                                   const void* __restrict__ Wfc,
                                                   const void* __restrict__ bfc,
                                                   void* __restrict__ out, int n,
                                                   const int* __restrict__ flag) {
    const int isbf = *flag;
    __shared__ float Ws[112 * 16];
    for (int i = threadIdx.x; i < 112 * 16; i += 256) Ws[i] = gload(Wfc, i, isbf);
    __syncthreads();

    const int h    = threadIdx.x & 3;
    const int node = blockIdx.x * 64 + (threadIdx.x >> 2);
    if (node >= n) return;

    float4 acc = make_float4(gload(bfc, 4 * h + 0, isbf), gload(bfc, 4 * h + 1, isbf),
                             gload(bfc, 4 * h + 2, isbf), gload(bfc, 4 * h + 3, isbf));

    const unsigned short* x1 = f1 + (size_t)node * 64;
#pragma unroll
    for (int k4 = 0; k4 < 16; ++k4) {
        const ushort4 xu = *(const ushort4*)(x1 + 4 * k4);
        const float xa[4] = {bf2f(xu.x), bf2f(xu.y), bf2f(xu.z), bf2f(xu.w)};
#pragma unroll
        for (int j = 0; j < 4; ++j) {
            const float4 wv = *(const float4*)(Ws + (4 * k4 + j) * 16 + 4 * h);
            acc.x = fmaf(xa[j], wv.x, acc.x); acc.y = fmaf(xa[j], wv.y, acc.y);
            acc.z = fmaf(xa[j], wv.z, acc.z); acc.w = fmaf(xa[j], wv.w, acc.w);
        }
    }
    const unsigned short* x2 = f2 + (size_t)node * 32;
#pragma unroll
    for (int k4 = 0; k4 < 8; ++k4) {
        const ushort4 xu = *(const ushort4*)(x2 + 4 * k4);
        const float xa[4] = {bf2f(xu.x), bf2f(xu.y), bf2f(xu.z), bf2f(xu.w)};
#pragma unroll
        for (int j = 0; j < 4; ++j) {
            const float4 wv = *(const float4*)(Ws + (64 + 4 * k4 + j) * 16 + 4 * h);
            acc.x = fmaf(xa[j], wv.x, acc.x); acc.y = fmaf(xa[j], wv.y, acc.y);
            acc.z = fmaf(xa[j], wv.z, acc.z); acc.w = fmaf(xa[j], wv.w, acc.w);
        }
    }
    const unsigned short* x3 = f3 + (size_t)node * 16;
#pragma unroll
    for (int k4 = 0; k4 < 4; ++k4) {
        const ushort4 xu = *(const ushort4*)(x3 + 4 * k4);
        const float xa[4] = {bf2f(xu.x), bf2f(xu.y), bf2f(xu.z), bf2f(xu.w)};
#pragma unroll
        for (int j = 0; j < 4; ++j) {
            const float4 wv = *(const float4*)(Ws + (96 + 4 * k4 + j) * 16 + 4 * h);
            acc.x = fmaf(xa[j], wv.x, acc.x); acc.y = fmaf(xa[j], wv.y, acc.y);
            acc.z = fmaf(xa[j], wv.z, acc.z); acc.w = fmaf(xa[j], wv.w, acc.w);
        }
    }

    const float4 r = make_float4(fmaxf(acc.x, 0.f), fmaxf(acc.y, 0.f),
                                 fmaxf(acc.z, 0.f), fmaxf(acc.w, 0.f));
    const size_t o = (size_t)node * 16 + 4 * h;
    if (isbf) {
        ushort4 u;
        u.x = f2bfu(r.x); u.y = f2bfu(r.y); u.z = f2bfu(r.z); u.w = f2bfu(r.w);
        *(ushort4*)((unsigned short*)out + o) = u;
    } else {
        *(float4*)((float*)out + o) = r;
    }
}

// ---------- launch ----------
extern "C" void kernel_launch(void* const* d_in, const int* in_sizes, int n_in,
                              void* d_out, int out_size, void* d_ws, size_t ws_size,
                              hipStream_t stream) {
    const int*  edges = (const int*)d_in[0];
    const void* feat  = d_in[1];
    const void* W1    = d_in[2];
    const void* b1    = d_in[3];
    const void* W2    = d_in[4];
    const void* b2    = d_in[5];
    const void* W3    = d_in[6];
    const void* b3    = d_in[7];
    const void* Wfc   = d_in[8];
    const void* bfc   = d_in[9];

    const int E = in_sizes[0] / 2;
    const int N = in_sizes[1] / 128;
    const int* row = edges;
    const int* col = edges + E;

    const int B  = DIVUP(E, 8192);     // phase-A blocks
    const int NB = DIVUP(N, 256);      // col buckets / phase-B blocks
    const int NBB = NB * B;            // scan length

    // workspace (~77 MB):
    // flag | dinv[N] | cnt[N] | rowptr[N] | csr[E] | part[E]int2 | y bf16[64N] |
    // f1 bf16[64N] | f2 bf16[32N] | f3 bf16[16N] | cntRB[NBB] | seg_off[NBB] | bsum
    char* p = (char*)d_ws;
    int*   flag   = (int*)p;               p += 16;
    float* dinv   = (float*)p;             p += (size_t)N * 4;
    int*   cnt    = (int*)p;               p += (size_t)N * 4;
    int*   rowptr = (int*)p;               p += (size_t)N * 4;
    int*   csr    = (int*)p;               p += (size_t)E * 4;
    int2*  part   = (int2*)p;              p += (size_t)E * 8;
    unsigned short* y  = (unsigned short*)p; p += (size_t)N * 64 * 2;
    unsigned short* f1 = (unsigned short*)p; p += (size_t)N * 64 * 2;
    unsigned short* f2 = (unsigned short*)p; p += (size_t)N * 32 * 2;
    unsigned short* f3 = (unsigned short*)p; p += (size_t)N * 16 * 2;
    int*   cntRB  = (int*)p;               p += (size_t)NBB * 4;
    int*   segoff = (int*)p;               p += (size_t)NBB * 4;
    int*   bsum   = (int*)p;

    detect_dtype<<<1, 256, 0, stream>>>(feat, flag);

    // CSR build (also produces cnt, rowptr, dinv) — no global atomics
    parta_hist<<<B, 256, 0, stream>>>(col, cntRB, E, B, NB);
    const int nb = DIVUP(NBB, 1024);
    scan_block_sums<<<nb, 256, 0, stream>>>(cntRB, bsum, NBB);
    scan_bsum<<<1, 256, 0, stream>>>(bsum, nb);
    scan_final<<<nb, 256, 0, stream>>>(cntRB, bsum, segoff, NBB);
    parta_scatter<<<B, 256, 0, stream>>>(row, col, segoff, part, E, B, NB);
    csr_build<<<NB, 256, 0, stream>>>(part, segoff, rowptr, cnt, dinv, csr, E, B, NB, N);

    // layer 1: 128 -> 64  (TILE_N = 64)
    gemm_tile<128, 64, 0><<<DIVUP(N, 64), 256, 0, stream>>>(feat, W1, dinv, y, N, flag);
    aggregate<64><<<DIVUP(N, 4), 256, 0, stream>>>(y, csr, rowptr, cnt, dinv, b1, f1, N, flag);

    // layer 2: 64 -> 32  (TILE_N = 128)
    gemm_tile<64, 32, 1><<<DIVUP(N, 128), 256, 0, stream>>>(f1, W2, dinv, y, N, flag);
    aggregate<32><<<DIVUP(N, 8), 256, 0, stream>>>(y, csr, rowptr, cnt, dinv, b2, f2, N, flag);

    // layer 3: 32 -> 16  (TILE_N = 256)
    gemm_tile<32, 16, 1><<<DIVUP(N, 256), 256, 0, stream>>>(f2, W3, dinv, y, N, flag);
    aggregate<16><<<DIVUP(N, 16), 256, 0, stream>>>(y, csr, rowptr, cnt, dinv, b3, f3, N, flag);

    // dense head
    head_kernel<<<DIVUP(N, 64), 256, 0, stream>>>(f1, f2, f3, Wfc, bfc, d_out, N, flag);
}

// Round 7
// 495.949 us; speedup vs baseline: 4.4489x; 1.0482x over previous
//
#include <hip/hip_runtime.h>
#include <hip/hip_bf16.h>

#define DIVUP(a, b) (((a) + (b) - 1) / (b))

// ---------- helpers ----------
__device__ __forceinline__ float bf2f(unsigned short u) {
    union { unsigned int i; float f; } v;
    v.i = ((unsigned int)u) << 16;
    return v.f;
}
__device__ __forceinline__ unsigned short f2bfu(float x) {
    return __hip_bfloat16_raw(__float2bfloat16(x)).x;   // RNE
}
__device__ __forceinline__ float gload(const void* p, int i, int isbf) {
    return isbf ? bf2f(((const unsigned short*)p)[i]) : ((const float*)p)[i];
}

// ---------- dtype detection (round-1 note; f32 vs bf16 inputs) ----------
__global__ void __launch_bounds__(256) detect_dtype(const void* __restrict__ feat,
                                                    int* __restrict__ flag) {
    __shared__ int cnt;
    if (threadIdx.x == 0) cnt = 0;
    __syncthreads();
    const unsigned short* u = (const unsigned short*)feat;
    int c = 0;
#pragma unroll
    for (int rep = 0; rep < 4; ++rep) {
        const int idx = threadIdx.x * 2 + rep * 512;
        const float v = fabsf(bf2f(u[idx]));
        c += (v > 1e-4f && v < 10.0f) ? 1 : 0;
    }
    atomicAdd(&cnt, c);
    __syncthreads();
    if (threadIdx.x == 0) *flag = (cnt > 512) ? 1 : 0;
}

// ================= CSR build: counting sort, zero global atomics =================
// bucket = col >> 8. cntRB[bucket*B + block] -> scan -> seg_off (bucket-major).
// Single-owner random writes only (round-4/5: multi-XCD random stores = 160us).

__global__ void __launch_bounds__(256) parta_hist(const int* __restrict__ col,
                                                  int* __restrict__ cntRB,
                                                  int E, int B, int NB) {
    __shared__ int h[512];
    for (int i = threadIdx.x; i < NB; i += 256) h[i] = 0;
    __syncthreads();
    const int base = blockIdx.x * 8192;
#pragma unroll
    for (int k = 0; k < 32; ++k) {
        const int e = base + k * 256 + threadIdx.x;
        if (e < E) atomicAdd(&h[col[e] >> 8], 1);
    }
    __syncthreads();
    for (int i = threadIdx.x; i < NB; i += 256) cntRB[i * B + blockIdx.x] = h[i];
}

// ---------- generic 3-phase exclusive scan ----------
__global__ void __launch_bounds__(256) scan_block_sums(const int* __restrict__ cnt,
                                                       int* __restrict__ bsum, int n) {
    __shared__ int red[256];
    const int base = blockIdx.x * 1024;
    int s = 0;
    for (int i = threadIdx.x; i < 1024; i += 256) {
        const int idx = base + i;
        s += (idx < n) ? cnt[idx] : 0;
    }
    red[threadIdx.x] = s;
    __syncthreads();
    for (int off = 128; off > 0; off >>= 1) {
        if (threadIdx.x < off) red[threadIdx.x] += red[threadIdx.x + off];
        __syncthreads();
    }
    if (threadIdx.x == 0) bsum[blockIdx.x] = red[0];
}

__global__ void __launch_bounds__(256) scan_bsum(int* __restrict__ bsum, int nb) {
    __shared__ int tmp[256];
    const int x = threadIdx.x;
    const int v = (x < nb) ? bsum[x] : 0;
    tmp[x] = v;
    __syncthreads();
    int val = v;
    for (int off = 1; off < 256; off <<= 1) {
        const int t = (x >= off) ? tmp[x - off] : 0;
        __syncthreads();
        val += t;
        tmp[x] = val;
        __syncthreads();
    }
    if (x < nb) bsum[x] = val - v;   // exclusive
}

__global__ void __launch_bounds__(256) scan_final(const int* __restrict__ cnt,
                                                  const int* __restrict__ bsum,
                                                  int* __restrict__ outp, int n) {
    __shared__ int tsum[256];
    const int base = blockIdx.x * 1024;
    const int x = threadIdx.x;
    int v[4];
    int s = 0;
#pragma unroll
    for (int k = 0; k < 4; ++k) {
        const int idx = base + x * 4 + k;
        v[k] = (idx < n) ? cnt[idx] : 0;
        s += v[k];
    }
    tsum[x] = s;
    __syncthreads();
    int val = s;
    for (int off = 1; off < 256; off <<= 1) {
        const int t = (x >= off) ? tsum[x - off] : 0;
        __syncthreads();
        val += t;
        tsum[x] = val;
        __syncthreads();
    }
    int prefix = bsum[blockIdx.x] + (val - s);
#pragma unroll
    for (int k = 0; k < 4; ++k) {
        const int idx = base + x * 4 + k;
        if (idx < n) outp[idx] = prefix;
        prefix += v[k];
    }
}

// ---------- phase A scatter: partition pairs into bucket segments ----------
__global__ void __launch_bounds__(256) parta_scatter(const int* __restrict__ row,
                                                     const int* __restrict__ col,
                                                     const int* __restrict__ seg_off,
                                                     int2* __restrict__ part,
                                                     int E, int B, int NB) {
    __shared__ int cur[512];
    for (int i = threadIdx.x; i < NB; i += 256) cur[i] = seg_off[i * B + blockIdx.x];
    __syncthreads();
    const int base = blockIdx.x * 8192;
#pragma unroll
    for (int k = 0; k < 32; ++k) {
        const int e = base + k * 256 + threadIdx.x;
        if (e < E) {
            const int c = col[e];
            const int r = row[e];
            const int p = atomicAdd(&cur[c >> 8], 1);
            part[p] = make_int2(c, r);
        }
    }
}

// ---------- phase B: per-range CSR build + degrees + dinv ----------
__global__ void __launch_bounds__(256) csr_build(const int2* __restrict__ part,
                                                 const int* __restrict__ seg_off,
                                                 int* __restrict__ rowptr,
                                                 int* __restrict__ cnt,
                                                 float* __restrict__ dinv,
                                                 int* __restrict__ csr,
                                                 int E, int B, int NB, int N) {
    __shared__ int cl[256];
    __shared__ int sc[256];
    const int r  = blockIdx.x;
    const int c0 = r << 8;
    const int s0 = seg_off[r * B];
    const int s1 = (r == NB - 1) ? E : seg_off[(r + 1) * B];
    cl[threadIdx.x] = 0;
    __syncthreads();
    for (int i = s0 + threadIdx.x; i < s1; i += 256)
        atomicAdd(&cl[part[i].x - c0], 1);
    __syncthreads();
    const int v = cl[threadIdx.x];
    sc[threadIdx.x] = v;
    __syncthreads();
    int val = v;
    for (int off = 1; off < 256; off <<= 1) {
        const int t = (threadIdx.x >= off) ? sc[threadIdx.x - off] : 0;
        __syncthreads();
        val += t;
        sc[threadIdx.x] = val;
        __syncthreads();
    }
    const int excl = val - v;
    const int c = c0 + threadIdx.x;
    if (c < N) {
        rowptr[c] = s0 + excl;
        cnt[c]    = v;
        dinv[c]   = rsqrtf((float)v + 1.0f);
    }
    cl[threadIdx.x] = s0 + excl;   // reuse as cursor
    __syncthreads();
    for (int i = s0 + threadIdx.x; i < s1; i += 256) {
        const int2 pr = part[i];
        const int p = atomicAdd(&cl[pr.x - c0], 1);
        csr[p] = pr.y << 7;        // row*128: byte offset template, shifted per layer
    }
}

// ================= layers =================

// register-tiled GEMM: y = bf16((x @ W) * dinv[node])
// XMODE: 0 = x dtype per flag (raw input), 1 = x bf16 (internal).
// SPLIT: F_OUT=64 output split into y_lo[N][32] / y_hi[N][32] half buffers
// (64B rows -> 6.4MB working set per aggregate half-pass, fits ~L2).
template<int F_IN, int F_OUT, int XMODE, int SPLIT>
__global__ void __launch_bounds__(256) gemm_tile(const void* __restrict__ x,
                                                 const void* __restrict__ W,
                                                 const float* __restrict__ dinv,
                                                 unsigned short* __restrict__ ylo,
                                                 unsigned short* __restrict__ yhi,
                                                 int n, const int* __restrict__ flag) {
    constexpr int TILE_N = 4096 / F_OUT;        // 64 / 128 / 256
    const int isbf = *flag;
    __shared__ float Ws[F_IN * F_OUT];
    __shared__ float xs[F_IN * TILE_N];

    const int t = threadIdx.x;
    for (int i = t; i < F_IN * F_OUT; i += 256) Ws[i] = gload(W, i, isbf);

    const int nb = blockIdx.x * TILE_N;
    for (int idx = t; idx < TILE_N * F_IN / 4; idx += 256) {
        const int nl = idx % TILE_N;
        const int k4 = idx / TILE_N;
        const int ng = nb + nl;
        float4 v = make_float4(0.f, 0.f, 0.f, 0.f);
        if (ng < n) {
            if (XMODE == 1 || isbf) {
                const ushort4 u = *(const ushort4*)((const unsigned short*)x +
                                                    (size_t)ng * F_IN + 4 * k4);
                v = make_float4(bf2f(u.x), bf2f(u.y), bf2f(u.z), bf2f(u.w));
            } else {
                v = *(const float4*)((const float*)x + (size_t)ng * F_IN + 4 * k4);
            }
        }
        xs[(4 * k4 + 0) * TILE_N + nl] = v.x;
        xs[(4 * k4 + 1) * TILE_N + nl] = v.y;
        xs[(4 * k4 + 2) * TILE_N + nl] = v.z;
        xs[(4 * k4 + 3) * TILE_N + nl] = v.w;
    }
    __syncthreads();

    const int h = t % (F_OUT / 4);
    const int g = t / (F_OUT / 4);

    float4 acc0 = make_float4(0.f, 0.f, 0.f, 0.f);
    float4 acc1 = acc0, acc2 = acc0, acc3 = acc0;

#pragma unroll 8
    for (int k = 0; k < F_IN; ++k) {
        const float4 wv = *(const float4*)(Ws + k * F_OUT + 4 * h);
        const float4 xv = *(const float4*)(xs + k * TILE_N + 4 * g);
        acc0.x = fmaf(xv.x, wv.x, acc0.x); acc0.y = fmaf(xv.x, wv.y, acc0.y);
        acc0.z = fmaf(xv.x, wv.z, acc0.z); acc0.w = fmaf(xv.x, wv.w, acc0.w);
        acc1.x = fmaf(xv.y, wv.x, acc1.x); acc1.y = fmaf(xv.y, wv.y, acc1.y);
        acc1.z = fmaf(xv.y, wv.z, acc1.z); acc1.w = fmaf(xv.y, wv.w, acc1.w);
        acc2.x = fmaf(xv.z, wv.x, acc2.x); acc2.y = fmaf(xv.z, wv.y, acc2.y);
        acc2.z = fmaf(xv.z, wv.z, acc2.z); acc2.w = fmaf(xv.z, wv.w, acc2.w);
        acc3.x = fmaf(xv.w, wv.x, acc3.x); acc3.y = fmaf(xv.w, wv.y, acc3.y);
        acc3.z = fmaf(xv.w, wv.z, acc3.z); acc3.w = fmaf(xv.w, wv.w, acc3.w);
    }

    float4 accs[4] = {acc0, acc1, acc2, acc3};
#pragma unroll
    for (int i = 0; i < 4; ++i) {
        const int ng = nb + 4 * g + i;
        if (ng < n) {
            const float s = dinv[ng];
            const float4 rr = accs[i];
            ushort4 u;
            u.x = f2bfu(rr.x * s); u.y = f2bfu(rr.y * s);
            u.z = f2bfu(rr.z * s); u.w = f2bfu(rr.w * s);
            if (SPLIT) {
                unsigned short* dst = (h < F_OUT / 8)
                    ? ylo + (size_t)ng * (F_OUT / 2) + 4 * h
                    : yhi + (size_t)ng * (F_OUT / 2) + 4 * h - F_OUT / 2;
                *(ushort4*)dst = u;
            } else {
                *(ushort4*)(ylo + (size_t)ng * F_OUT + 4 * h) = u;
            }
        }
    }
}

// aggregate + fused epilogue: out[node*OSTR + fofs + f] =
//   bf16(relu(dinv*(sum_neighbors y[r] + y_self) + b[fofs+f]))
// csr entries = row<<7; y row stride = 128>>SH bytes.
// 16-deep gather unroll: ~16 independent HBM loads in flight per lane group
// (round-6 counters: unroll-4 was latency-bound at 2.4x the BW floor).
template<int F, int SH>
__global__ void __launch_bounds__(256) aggregate(const unsigned short* __restrict__ y,
                                                 const int* __restrict__ csr,
                                                 const int* __restrict__ rowptr,
                                                 const int* __restrict__ cnt,
                                                 const float* __restrict__ dinv,
                                                 const void* __restrict__ b,
                                                 unsigned short* __restrict__ out,
                                                 int n, int OSTR, int fofs,
                                                 const int* __restrict__ flag) {
    const int isbf = *flag;
    constexpr int GP = 64 / F;
    const int lane = threadIdx.x & 63;
    const int sub  = lane / F;
    const int f    = lane % F;
    const int wave = (blockIdx.x * 256 + threadIdx.x) >> 6;
    const int node = wave * GP + sub;
    if (node >= n) return;

    const int beg = rowptr[node];
    const int deg = cnt[node];
    const char* yb = (const char*)y;
    const int f2b = f * 2;
    float acc = 0.f;
    int j = 0;
    for (; j + 16 <= deg; j += 16) {
        int o[16];
#pragma unroll
        for (int k = 0; k < 16; ++k) o[k] = csr[beg + j + k] >> SH;
        float v[16];
#pragma unroll
        for (int k = 0; k < 16; ++k)
            v[k] = bf2f(*(const unsigned short*)(yb + o[k] + f2b));
        const float s0 = ((v[0] + v[1]) + (v[2] + v[3])) + ((v[4] + v[5]) + (v[6] + v[7]));
        const float s1 = ((v[8] + v[9]) + (v[10] + v[11])) + ((v[12] + v[13]) + (v[14] + v[15]));
        acc += s0 + s1;
    }
    for (; j + 4 <= deg; j += 4) {
        int o[4];
#pragma unroll
        for (int k = 0; k < 4; ++k) o[k] = csr[beg + j + k] >> SH;
        float v[4];
#pragma unroll
        for (int k = 0; k < 4; ++k)
            v[k] = bf2f(*(const unsigned short*)(yb + o[k] + f2b));
        acc += (v[0] + v[1]) + (v[2] + v[3]);
    }
    for (; j < deg; ++j)
        acc += bf2f(*(const unsigned short*)(yb + (csr[beg + j] >> SH) + f2b));

    const float self = bf2f(y[(size_t)node * F + f]);
    const float v = dinv[node] * (acc + self) + gload(b, fofs + f, isbf);
    out[(size_t)node * OSTR + fofs + f] = f2bfu(fmaxf(v, 0.f));
}

// dense head: out = relu(concat(f1,f2,f3) @ Wfc + bfc); f-buffers bf16
__global__ void __launch_bounds__(256) head_kernel(const unsigned short* __restrict__ f1,
                                                   const unsigned short* __restrict__ f2,
                                                   const unsigned short* __restrict__ f3,
                                                   const void* __restrict__ Wfc,
                                                   const void* __restrict__ bfc,
                                                   void* __restrict__ out, int n,
                                                   const int* __restrict__ flag) {
    const int isbf = *flag;
    __shared__ float Ws[112 * 16];
    for (int i = threadIdx.x; i < 112 * 16; i += 256) Ws[i] = gload(Wfc, i, isbf);
    __syncthreads();

    const int h    = threadIdx.x & 3;
    const int node = blockIdx.x * 64 + (threadIdx.x >> 2);
    if (node >= n) return;

    float4 acc = make_float4(gload(bfc, 4 * h + 0, isbf), gload(bfc, 4 * h + 1, isbf),
                             gload(bfc, 4 * h + 2, isbf), gload(bfc, 4 * h + 3, isbf));

    const unsigned short* x1 = f1 + (size_t)node * 64;
#pragma unroll
    for (int k4 = 0; k4 < 16; ++k4) {
        const ushort4 xu = *(const ushort4*)(x1 + 4 * k4);
        const float xa[4] = {bf2f(xu.x), bf2f(xu.y), bf2f(xu.z), bf2f(xu.w)};
#pragma unroll
        for (int j = 0; j < 4; ++j) {
            const float4 wv = *(const float4*)(Ws + (4 * k4 + j) * 16 + 4 * h);
            acc.x = fmaf(xa[j], wv.x, acc.x); acc.y = fmaf(xa[j], wv.y, acc.y);
            acc.z = fmaf(xa[j], wv.z, acc.z); acc.w = fmaf(xa[j], wv.w, acc.w);
        }
    }
    const unsigned short* x2 = f2 + (size_t)node * 32;
#pragma unroll
    for (int k4 = 0; k4 < 8; ++k4) {
        const ushort4 xu = *(const ushort4*)(x2 + 4 * k4);
        const float xa[4] = {bf2f(xu.x), bf2f(xu.y), bf2f(xu.z), bf2f(xu.w)};
#pragma unroll
        for (int j = 0; j < 4; ++j) {
            const float4 wv = *(const float4*)(Ws + (64 + 4 * k4 + j) * 16 + 4 * h);
            acc.x = fmaf(xa[j], wv.x, acc.x); acc.y = fmaf(xa[j], wv.y, acc.y);
            acc.z = fmaf(xa[j], wv.z, acc.z); acc.w = fmaf(xa[j], wv.w, acc.w);
        }
    }
    const unsigned short* x3 = f3 + (size_t)node * 16;
#pragma unroll
    for (int k4 = 0; k4 < 4; ++k4) {
        const ushort4 xu = *(const ushort4*)(x3 + 4 * k4);
        const float xa[4] = {bf2f(xu.x), bf2f(xu.y), bf2f(xu.z), bf2f(xu.w)};
#pragma unroll
        for (int j = 0; j < 4; ++j) {
            const float4 wv = *(const float4*)(Ws + (96 + 4 * k4 + j) * 16 + 4 * h);
            acc.x = fmaf(xa[j], wv.x, acc.x); acc.y = fmaf(xa[j], wv.y, acc.y);
            acc.z = fmaf(xa[j], wv.z, acc.z); acc.w = fmaf(xa[j], wv.w, acc.w);
        }
    }

    const float4 r = make_float4(fmaxf(acc.x, 0.f), fmaxf(acc.y, 0.f),
                                 fmaxf(acc.z, 0.f), fmaxf(acc.w, 0.f));
    const size_t o = (size_t)node * 16 + 4 * h;
    if (isbf) {
        ushort4 u;
        u.x = f2bfu(r.x); u.y = f2bfu(r.y); u.z = f2bfu(r.z); u.w = f2bfu(r.w);
        *(ushort4*)((unsigned short*)out + o) = u;
    } else {
        *(float4*)((float*)out + o) = r;
    }
}

// ---------- launch ----------
extern "C" void kernel_launch(void* const* d_in, const int* in_sizes, int n_in,
                              void* d_out, int out_size, void* d_ws, size_t ws_size,
                              hipStream_t stream) {
    const int*  edges = (const int*)d_in[0];
    const void* feat  = d_in[1];
    const void* W1    = d_in[2];
    const void* b1    = d_in[3];
    const void* W2    = d_in[4];
    const void* b2    = d_in[5];
    const void* W3    = d_in[6];
    const void* b3    = d_in[7];
    const void* Wfc   = d_in[8];
    const void* bfc   = d_in[9];

    const int E = in_sizes[0] / 2;
    const int N = in_sizes[1] / 128;
    const int* row = edges;
    const int* col = edges + E;

    const int B  = DIVUP(E, 8192);     // phase-A blocks
    const int NB = DIVUP(N, 256);      // col buckets / phase-B blocks
    const int NBB = NB * B;            // scan length

    // workspace (~77 MB):
    // flag | dinv[N] | cnt[N] | rowptr[N] | csr[E] | part[E]int2 |
    // y_lo bf16[32N] | y_hi bf16[32N] | f1 bf16[64N] | f2 bf16[32N] | f3 bf16[16N]
    // | cntRB[NBB] | seg_off[NBB] | bsum
    char* p = (char*)d_ws;
    int*   flag   = (int*)p;               p += 16;
    float* dinv   = (float*)p;             p += (size_t)N * 4;
    int*   cnt    = (int*)p;               p += (size_t)N * 4;
    int*   rowptr = (int*)p;               p += (size_t)N * 4;
    int*   csr    = (int*)p;               p += (size_t)E * 4;
    int2*  part   = (int2*)p;              p += (size_t)E * 8;
    unsigned short* ylo = (unsigned short*)p; p += (size_t)N * 32 * 2;
    unsigned short* yhi = (unsigned short*)p; p += (size_t)N * 32 * 2;
    unsigned short* f1 = (unsigned short*)p; p += (size_t)N * 64 * 2;
    unsigned short* f2 = (unsigned short*)p; p += (size_t)N * 32 * 2;
    unsigned short* f3 = (unsigned short*)p; p += (size_t)N * 16 * 2;
    int*   cntRB  = (int*)p;               p += (size_t)NBB * 4;
    int*   segoff = (int*)p;               p += (size_t)NBB * 4;
    int*   bsum   = (int*)p;

    detect_dtype<<<1, 256, 0, stream>>>(feat, flag);

    // CSR build (also produces cnt, rowptr, dinv) — no global atomics
    parta_hist<<<B, 256, 0, stream>>>(col, cntRB, E, B, NB);
    const int nb = DIVUP(NBB, 1024);
    scan_block_sums<<<nb, 256, 0, stream>>>(cntRB, bsum, NBB);
    scan_bsum<<<1, 256, 0, stream>>>(bsum, nb);
    scan_final<<<nb, 256, 0, stream>>>(cntRB, bsum, segoff, NBB);
    parta_scatter<<<B, 256, 0, stream>>>(row, col, segoff, part, E, B, NB);
    csr_build<<<NB, 256, 0, stream>>>(part, segoff, rowptr, cnt, dinv, csr, E, B, NB, N);

    // layer 1: 128 -> 64, split output halves; aggregate one half per pass
    gemm_tile<128, 64, 0, 1><<<DIVUP(N, 64), 256, 0, stream>>>(feat, W1, dinv, ylo, yhi, N, flag);
    aggregate<32, 1><<<DIVUP(N, 8), 256, 0, stream>>>(ylo, csr, rowptr, cnt, dinv, b1, f1, N, 64, 0, flag);
    aggregate<32, 1><<<DIVUP(N, 8), 256, 0, stream>>>(yhi, csr, rowptr, cnt, dinv, b1, f1, N, 64, 32, flag);

    // layer 2: 64 -> 32 (y reuses ylo region: N*32 bf16)
    gemm_tile<64, 32, 1, 0><<<DIVUP(N, 128), 256, 0, stream>>>(f1, W2, dinv, ylo, ylo, N, flag);
    aggregate<32, 1><<<DIVUP(N, 8), 256, 0, stream>>>(ylo, csr, rowptr, cnt, dinv, b2, f2, N, 32, 0, flag);

    // layer 3: 32 -> 16
    gemm_tile<32, 16, 1, 0><<<DIVUP(N, 256), 256, 0, stream>>>(f2, W3, dinv, ylo, ylo, N, flag);
    aggregate<16, 2><<<DIVUP(N, 16), 256, 0, stream>>>(ylo, csr, rowptr, cnt, dinv, b3, f3, N, 16, 0, flag);

    // dense head
    head_kernel<<<DIVUP(N, 64), 256, 0, stream>>>(f1, f2, f3, Wfc, bfc, d_out, N, flag);
}

// Round 8
// 455.079 us; speedup vs baseline: 4.8485x; 1.0898x over previous
//
#include <hip/hip_runtime.h>
#include <hip/hip_bf16.h>

#define DIVUP(a, b) (((a) + (b) - 1) / (b))

typedef __attribute__((ext_vector_type(8))) short bf16x8;
typedef __attribute__((ext_vector_type(4))) float f32x4;

// ---------- helpers ----------
__device__ __forceinline__ float bf2f(unsigned short u) {
    union { unsigned int i; float f; } v;
    v.i = ((unsigned int)u) << 16;
    return v.f;
}
__device__ __forceinline__ unsigned short f2bfu(float x) {
    return __hip_bfloat16_raw(__float2bfloat16(x)).x;   // RNE
}
__device__ __forceinline__ float gload(const void* p, int i, int isbf) {
    return isbf ? bf2f(((const unsigned short*)p)[i]) : ((const float*)p)[i];
}

// ---------- dtype detection (round-1 note; f32 vs bf16 inputs) ----------
__global__ void __launch_bounds__(256) detect_dtype(const void* __restrict__ feat,
                                                    int* __restrict__ flag) {
    __shared__ int cnt;
    if (threadIdx.x == 0) cnt = 0;
    __syncthreads();
    const unsigned short* u = (const unsigned short*)feat;
    int c = 0;
#pragma unroll
    for (int rep = 0; rep < 4; ++rep) {
        const int idx = threadIdx.x * 2 + rep * 512;
        const float v = fabsf(bf2f(u[idx]));
        c += (v > 1e-4f && v < 10.0f) ? 1 : 0;
    }
    atomicAdd(&cnt, c);
    __syncthreads();
    if (threadIdx.x == 0) *flag = (cnt > 512) ? 1 : 0;
}

// ================= CSR build: counting sort, zero global atomics =================
__global__ void __launch_bounds__(256) parta_hist(const int* __restrict__ col,
                                                  int* __restrict__ cntRB,
                                                  int E, int B, int NB) {
    __shared__ int h[512];
    for (int i = threadIdx.x; i < NB; i += 256) h[i] = 0;
    __syncthreads();
    const int base = blockIdx.x * 8192;
#pragma unroll
    for (int k = 0; k < 32; ++k) {
        const int e = base + k * 256 + threadIdx.x;
        if (e < E) atomicAdd(&h[col[e] >> 8], 1);
    }
    __syncthreads();
    for (int i = threadIdx.x; i < NB; i += 256) cntRB[i * B + blockIdx.x] = h[i];
}

__global__ void __launch_bounds__(256) scan_block_sums(const int* __restrict__ cnt,
                                                       int* __restrict__ bsum, int n) {
    __shared__ int red[256];
    const int base = blockIdx.x * 1024;
    int s = 0;
    for (int i = threadIdx.x; i < 1024; i += 256) {
        const int idx = base + i;
        s += (idx < n) ? cnt[idx] : 0;
    }
    red[threadIdx.x] = s;
    __syncthreads();
    for (int off = 128; off > 0; off >>= 1) {
        if (threadIdx.x < off) red[threadIdx.x] += red[threadIdx.x + off];
        __syncthreads();
    }
    if (threadIdx.x == 0) bsum[blockIdx.x] = red[0];
}

__global__ void __launch_bounds__(256) scan_bsum(int* __restrict__ bsum, int nb) {
    __shared__ int tmp[256];
    const int x = threadIdx.x;
    const int v = (x < nb) ? bsum[x] : 0;
    tmp[x] = v;
    __syncthreads();
    int val = v;
    for (int off = 1; off < 256; off <<= 1) {
        const int t = (x >= off) ? tmp[x - off] : 0;
        __syncthreads();
        val += t;
        tmp[x] = val;
        __syncthreads();
    }
    if (x < nb) bsum[x] = val - v;   // exclusive
}

__global__ void __launch_bounds__(256) scan_final(const int* __restrict__ cnt,
                                                  const int* __restrict__ bsum,
                                                  int* __restrict__ outp, int n) {
    __shared__ int tsum[256];
    const int base = blockIdx.x * 1024;
    const int x = threadIdx.x;
    int v[4];
    int s = 0;
#pragma unroll
    for (int k = 0; k < 4; ++k) {
        const int idx = base + x * 4 + k;
        v[k] = (idx < n) ? cnt[idx] : 0;
        s += v[k];
    }
    tsum[x] = s;
    __syncthreads();
    int val = s;
    for (int off = 1; off < 256; off <<= 1) {
        const int t = (x >= off) ? tsum[x - off] : 0;
        __syncthreads();
        val += t;
        tsum[x] = val;
        __syncthreads();
    }
    int prefix = bsum[blockIdx.x] + (val - s);
#pragma unroll
    for (int k = 0; k < 4; ++k) {
        const int idx = base + x * 4 + k;
        if (idx < n) outp[idx] = prefix;
        prefix += v[k];
    }
}

__global__ void __launch_bounds__(256) parta_scatter(const int* __restrict__ row,
                                                     const int* __restrict__ col,
                                                     const int* __restrict__ seg_off,
                                                     int2* __restrict__ part,
                                                     int E, int B, int NB) {
    __shared__ int cur[512];
    for (int i = threadIdx.x; i < NB; i += 256) cur[i] = seg_off[i * B + blockIdx.x];
    __syncthreads();
    const int base = blockIdx.x * 8192;
#pragma unroll
    for (int k = 0; k < 32; ++k) {
        const int e = base + k * 256 + threadIdx.x;
        if (e < E) {
            const int c = col[e];
            const int r = row[e];
            const int p = atomicAdd(&cur[c >> 8], 1);
            part[p] = make_int2(c, r);
        }
    }
}

__global__ void __launch_bounds__(256) csr_build(const int2* __restrict__ part,
                                                 const int* __restrict__ seg_off,
                                                 int* __restrict__ rowptr,
                                                 int* __restrict__ cnt,
                                                 float* __restrict__ dinv,
                                                 int* __restrict__ csr,
                                                 int E, int B, int NB, int N) {
    __shared__ int cl[256];
    __shared__ int sc[256];
    const int r  = blockIdx.x;
    const int c0 = r << 8;
    const int s0 = seg_off[r * B];
    const int s1 = (r == NB - 1) ? E : seg_off[(r + 1) * B];
    cl[threadIdx.x] = 0;
    __syncthreads();
    for (int i = s0 + threadIdx.x; i < s1; i += 256)
        atomicAdd(&cl[part[i].x - c0], 1);
    __syncthreads();
    const int v = cl[threadIdx.x];
    sc[threadIdx.x] = v;
    __syncthreads();
    int val = v;
    for (int off = 1; off < 256; off <<= 1) {
        const int t = (threadIdx.x >= off) ? sc[threadIdx.x - off] : 0;
        __syncthreads();
        val += t;
        sc[threadIdx.x] = val;
        __syncthreads();
    }
    const int excl = val - v;
    const int c = c0 + threadIdx.x;
    if (c < N) {
        rowptr[c] = s0 + excl;
        cnt[c]    = v;
        dinv[c]   = rsqrtf((float)v + 1.0f);
    }
    cl[threadIdx.x] = s0 + excl;   // reuse as cursor
    __syncthreads();
    for (int i = s0 + threadIdx.x; i < s1; i += 256) {
        const int2 pr = part[i];
        const int p = atomicAdd(&cl[pr.x - c0], 1);
        csr[p] = pr.y << 7;        // row*128: byte offset template, shifted per layer
    }
}

// ================= MFMA GEMM: y = bf16((x @ W) * dinv[node]) =================
// Block = 4 waves x 16 nodes. Verified layouts (cdna docs m89/m91/m120):
//   A[m=lane&15][k=quad*8+j]   <- loaded straight from global (row node, k-chunk)
//   B[k=quad*8+j][n=lane&15]   <- ds_read_b128 from transposed Wt[n][k]
//   D col=lane&15, row=quad*4+reg
// LDS = Wt only (17/4.6/1.3 KB) -> occupancy no longer LDS-bound
// (round-7 counters: 64KB-LDS VALU gemm ran at 17% occupancy, 67us).
template<int F_IN, int F_OUT, int XMODE, int SPLIT>
__global__ void __launch_bounds__(256) gemm_mfma(const void* __restrict__ x,
                                                 const void* __restrict__ W,
                                                 const float* __restrict__ dinv,
                                                 unsigned short* __restrict__ ylo,
                                                 unsigned short* __restrict__ yhi,
                                                 int n, const int* __restrict__ flag) {
    constexpr int KS = F_IN / 32;        // k-slices
    constexpr int NT = F_OUT / 16;       // f-tiles
    constexpr int WPAD = F_IN + 8;       // +16B row pad vs bank conflicts
    const int isbf = *flag;
    __shared__ unsigned short Wt[F_OUT * WPAD];

    for (int i = threadIdx.x; i < F_IN * F_OUT; i += 256) {
        const int k = i / F_OUT, nn = i % F_OUT;
        Wt[nn * WPAD + k] = f2bfu(gload(W, i, isbf));
    }
    __syncthreads();

    const int lane = threadIdx.x & 63;
    const int wid  = threadIdx.x >> 6;
    const int m    = lane & 15;
    const int quad = lane >> 4;
    const int nodeA = blockIdx.x * 64 + wid * 16 + m;

    bf16x8 afr[KS];
    if (nodeA < n) {
        if (XMODE == 1 || isbf) {
            const unsigned short* xr = (const unsigned short*)x + (size_t)nodeA * F_IN;
#pragma unroll
            for (int s = 0; s < KS; ++s)
                afr[s] = *(const bf16x8*)(xr + s * 32 + quad * 8);
        } else {
            const float* xr = (const float*)x + (size_t)nodeA * F_IN;
#pragma unroll
            for (int s = 0; s < KS; ++s) {
                const float4 v0 = *(const float4*)(xr + s * 32 + quad * 8);
                const float4 v1 = *(const float4*)(xr + s * 32 + quad * 8 + 4);
                bf16x8 a;
                a[0] = (short)f2bfu(v0.x); a[1] = (short)f2bfu(v0.y);
                a[2] = (short)f2bfu(v0.z); a[3] = (short)f2bfu(v0.w);
                a[4] = (short)f2bfu(v1.x); a[5] = (short)f2bfu(v1.y);
                a[6] = (short)f2bfu(v1.z); a[7] = (short)f2bfu(v1.w);
                afr[s] = a;
            }
        }
    } else {
#pragma unroll
        for (int s = 0; s < KS; ++s) afr[s] = (bf16x8)(short)0;
    }

    f32x4 acc[NT];
#pragma unroll
    for (int t = 0; t < NT; ++t) acc[t] = (f32x4)0.f;

#pragma unroll
    for (int t = 0; t < NT; ++t) {
#pragma unroll
        for (int s = 0; s < KS; ++s) {
            const bf16x8 bfr = *(const bf16x8*)(Wt + (t * 16 + m) * WPAD + s * 32 + quad * 8);
            acc[t] = __builtin_amdgcn_mfma_f32_16x16x32_bf16(afr[s], bfr, acc[t], 0, 0, 0);
        }
    }

#pragma unroll
    for (int r = 0; r < 4; ++r) {
        const int ng = blockIdx.x * 64 + wid * 16 + quad * 4 + r;
        if (ng < n) {
            const float scl = dinv[ng];
#pragma unroll
            for (int t = 0; t < NT; ++t) {
                const int f = t * 16 + m;
                const unsigned short v = f2bfu(acc[t][r] * scl);
                if (SPLIT) {
                    if (t < NT / 2) ylo[(size_t)ng * (F_OUT / 2) + f] = v;
                    else            yhi[(size_t)ng * (F_OUT / 2) + f - F_OUT / 2] = v;
                } else {
                    ylo[(size_t)ng * F_OUT + f] = v;
                }
            }
        }
    }
}

// ---------- aggregate + fused epilogue (16-deep MLP unroll) ----------
template<int F, int SH>
__global__ void __launch_bounds__(256) aggregate(const unsigned short* __restrict__ y,
                                                 const int* __restrict__ csr,
                                                 const int* __restrict__ rowptr,
                                                 const int* __restrict__ cnt,
                                                 const float* __restrict__ dinv,
                                                 const void* __restrict__ b,
                                                 unsigned short* __restrict__ out,
                                                 int n, int OSTR, int fofs,
                                                 const int* __restrict__ flag) {
    const int isbf = *flag;
    constexpr int GP = 64 / F;
    const int lane = threadIdx.x & 63;
    const int sub  = lane / F;
    const int f    = lane % F;
    const int wave = (blockIdx.x * 256 + threadIdx.x) >> 6;
    const int node = wave * GP + sub;
    if (node >= n) return;

    const int beg = rowptr[node];
    const int deg = cnt[node];
    const char* yb = (const char*)y;
    const int f2b = f * 2;
    float acc = 0.f;
    int j = 0;
    for (; j + 16 <= deg; j += 16) {
        int o[16];
#pragma unroll
        for (int k = 0; k < 16; ++k) o[k] = csr[beg + j + k] >> SH;
        float v[16];
#pragma unroll
        for (int k = 0; k < 16; ++k)
            v[k] = bf2f(*(const unsigned short*)(yb + o[k] + f2b));
        const float s0 = ((v[0] + v[1]) + (v[2] + v[3])) + ((v[4] + v[5]) + (v[6] + v[7]));
        const float s1 = ((v[8] + v[9]) + (v[10] + v[11])) + ((v[12] + v[13]) + (v[14] + v[15]));
        acc += s0 + s1;
    }
    for (; j + 4 <= deg; j += 4) {
        int o[4];
#pragma unroll
        for (int k = 0; k < 4; ++k) o[k] = csr[beg + j + k] >> SH;
        float v[4];
#pragma unroll
        for (int k = 0; k < 4; ++k)
            v[k] = bf2f(*(const unsigned short*)(yb + o[k] + f2b));
        acc += (v[0] + v[1]) + (v[2] + v[3]);
    }
    for (; j < deg; ++j)
        acc += bf2f(*(const unsigned short*)(yb + (csr[beg + j] >> SH) + f2b));

    const float self = bf2f(y[(size_t)node * F + f]);
    const float v = dinv[node] * (acc + self) + gload(b, fofs + f, isbf);
    out[(size_t)node * OSTR + fofs + f] = f2bfu(fmaxf(v, 0.f));
}

// ---------- dense head: out = relu(concat(f1,f2,f3) @ Wfc + bfc) ----------
__global__ void __launch_bounds__(256) head_kernel(const unsigned short* __restrict__ f1,
                                                   const unsigned short* __restrict__ f2,
                                                   const unsigned short* __restrict__ f3,
                                                   const void* __restrict__ Wfc,
                                                   const void* __restrict__ bfc,
                                                   void* __restrict__ out, int n,
                                                   const int* __restrict__ flag) {
    const int isbf = *flag;
    __shared__ float Ws[112 * 16];
    for (int i = threadIdx.x; i < 112 * 16; i += 256) Ws[i] = gload(Wfc, i, isbf);
    __syncthreads();

    const int h    = threadIdx.x & 3;
    const int node = blockIdx.x * 64 + (threadIdx.x >> 2);
    if (node >= n) return;

    float4 acc = make_float4(gload(bfc, 4 * h + 0, isbf), gload(bfc, 4 * h + 1, isbf),
                             gload(bfc, 4 * h + 2, isbf), gload(bfc, 4 * h + 3, isbf));

    const unsigned short* x1 = f1 + (size_t)node * 64;
#pragma unroll
    for (int k4 = 0; k4 < 16; ++k4) {
        const ushort4 xu = *(const ushort4*)(x1 + 4 * k4);
        const float xa[4] = {bf2f(xu.x), bf2f(xu.y), bf2f(xu.z), bf2f(xu.w)};
#pragma unroll
        for (int j = 0; j < 4; ++j) {
            const float4 wv = *(const float4*)(Ws + (4 * k4 + j) * 16 + 4 * h);
            acc.x = fmaf(xa[j], wv.x, acc.x); acc.y = fmaf(xa[j], wv.y, acc.y);
            acc.z = fmaf(xa[j], wv.z, acc.z); acc.w = fmaf(xa[j], wv.w, acc.w);
        }
    }
    const unsigned short* x2 = f2 + (size_t)node * 32;
#pragma unroll
    for (int k4 = 0; k4 < 8; ++k4) {
        const ushort4 xu = *(const ushort4*)(x2 + 4 * k4);
        const float xa[4] = {bf2f(xu.x), bf2f(xu.y), bf2f(xu.z), bf2f(xu.w)};
#pragma unroll
        for (int j = 0; j < 4; ++j) {
            const float4 wv = *(const float4*)(Ws + (64 + 4 * k4 + j) * 16 + 4 * h);
            acc.x = fmaf(xa[j], wv.x, acc.x); acc.y = fmaf(xa[j], wv.y, acc.y);
            acc.z = fmaf(xa[j], wv.z, acc.z); acc.w = fmaf(xa[j], wv.w, acc.w);
        }
    }
    const unsigned short* x3 = f3 + (size_t)node * 16;
#pragma unroll
    for (int k4 = 0; k4 < 4; ++k4) {
        const ushort4 xu = *(const ushort4*)(x3 + 4 * k4);
        const float xa[4] = {bf2f(xu.x), bf2f(xu.y), bf2f(xu.z), bf2f(xu.w)};
#pragma unroll
        for (int j = 0; j < 4; ++j) {
            const float4 wv = *(const float4*)(Ws + (96 + 4 * k4 + j) * 16 + 4 * h);
            acc.x = fmaf(xa[j], wv.x, acc.x); acc.y = fmaf(xa[j], wv.y, acc.y);
            acc.z = fmaf(xa[j], wv.z, acc.z); acc.w = fmaf(xa[j], wv.w, acc.w);
        }
    }

    const float4 r = make_float4(fmaxf(acc.x, 0.f), fmaxf(acc.y, 0.f),
                                 fmaxf(acc.z, 0.f), fmaxf(acc.w, 0.f));
    const size_t o = (size_t)node * 16 + 4 * h;
    if (isbf) {
        ushort4 u;
        u.x = f2bfu(r.x); u.y = f2bfu(r.y); u.z = f2bfu(r.z); u.w = f2bfu(r.w);
        *(ushort4*)((unsigned short*)out + o) = u;
    } else {
        *(float4*)((float*)out + o) = r;
    }
}

// ---------- launch ----------
extern "C" void kernel_launch(void* const* d_in, const int* in_sizes, int n_in,
                              void* d_out, int out_size, void* d_ws, size_t ws_size,
                              hipStream_t stream) {
    const int*  edges = (const int*)d_in[0];
    const void* feat  = d_in[1];
    const void* W1    = d_in[2];
    const void* b1    = d_in[3];
    const void* W2    = d_in[4];
    const void* b2    = d_in[5];
    const void* W3    = d_in[6];
    const void* b3    = d_in[7];
    const void* Wfc   = d_in[8];
    const void* bfc   = d_in[9];

    const int E = in_sizes[0] / 2;
    const int N = in_sizes[1] / 128;
    const int* row = edges;
    const int* col = edges + E;

    const int B  = DIVUP(E, 8192);     // phase-A blocks
    const int NB = DIVUP(N, 256);      // col buckets / phase-B blocks
    const int NBB = NB * B;            // scan length

    char* p = (char*)d_ws;
    int*   flag   = (int*)p;               p += 16;
    float* dinv   = (float*)p;             p += (size_t)N * 4;
    int*   cnt    = (int*)p;               p += (size_t)N * 4;
    int*   rowptr = (int*)p;               p += (size_t)N * 4;
    int*   csr    = (int*)p;               p += (size_t)E * 4;
    int2*  part   = (int2*)p;              p += (size_t)E * 8;
    unsigned short* ylo = (unsigned short*)p; p += (size_t)N * 32 * 2;
    unsigned short* yhi = (unsigned short*)p; p += (size_t)N * 32 * 2;
    unsigned short* f1 = (unsigned short*)p; p += (size_t)N * 64 * 2;
    unsigned short* f2 = (unsigned short*)p; p += (size_t)N * 32 * 2;
    unsigned short* f3 = (unsigned short*)p; p += (size_t)N * 16 * 2;
    int*   cntRB  = (int*)p;               p += (size_t)NBB * 4;
    int*   segoff = (int*)p;               p += (size_t)NBB * 4;
    int*   bsum   = (int*)p;

    detect_dtype<<<1, 256, 0, stream>>>(feat, flag);

    // CSR build (also produces cnt, rowptr, dinv) — no global atomics
    parta_hist<<<B, 256, 0, stream>>>(col, cntRB, E, B, NB);
    const int nb = DIVUP(NBB, 1024);
    scan_block_sums<<<nb, 256, 0, stream>>>(cntRB, bsum, NBB);
    scan_bsum<<<1, 256, 0, stream>>>(bsum, nb);
    scan_final<<<nb, 256, 0, stream>>>(cntRB, bsum, segoff, NBB);
    parta_scatter<<<B, 256, 0, stream>>>(row, col, segoff, part, E, B, NB);
    csr_build<<<NB, 256, 0, stream>>>(part, segoff, rowptr, cnt, dinv, csr, E, B, NB, N);

    // layer 1: 128 -> 64 (split halves); aggregate one half per pass
    gemm_mfma<128, 64, 0, 1><<<DIVUP(N, 64), 256, 0, stream>>>(feat, W1, dinv, ylo, yhi, N, flag);
    aggregate<32, 1><<<DIVUP(N, 8), 256, 0, stream>>>(ylo, csr, rowptr, cnt, dinv, b1, f1, N, 64, 0, flag);
    aggregate<32, 1><<<DIVUP(N, 8), 256, 0, stream>>>(yhi, csr, rowptr, cnt, dinv, b1, f1, N, 64, 32, flag);

    // layer 2: 64 -> 32 (y reuses ylo region)
    gemm_mfma<64, 32, 1, 0><<<DIVUP(N, 64), 256, 0, stream>>>(f1, W2, dinv, ylo, ylo, N, flag);
    aggregate<32, 1><<<DIVUP(N, 8), 256, 0, stream>>>(ylo, csr, rowptr, cnt, dinv, b2, f2, N, 32, 0, flag);

    // layer 3: 32 -> 16
    gemm_mfma<32, 16, 1, 0><<<DIVUP(N, 64), 256, 0, stream>>>(f2, W3, dinv, ylo, ylo, N, flag);
    aggregate<16, 2><<<DIVUP(N, 16), 256, 0, stream>>>(ylo, csr, rowptr, cnt, dinv, b3, f3, N, 16, 0, flag);

    // dense head
    head_kernel<<<DIVUP(N, 64), 256, 0, stream>>>(f1, f2, f3, Wfc, bfc, d_out, N, flag);
}